// Round 1
// baseline (574.691 us; speedup 1.0000x reference)
//
#include <hip/hip_runtime.h>
#include <stdint.h>

#define B_ 8
#define S_ 128
#define R_ 41
#define F_ 768
#define NH_ 8
#define HID_ 96
#define BS_ (B_*S_)
#define SM_SCALE 256.0f

typedef _Float16 f16;
typedef _Float16 f16x8 __attribute__((ext_vector_type(8)));
typedef _Float16 f16x4 __attribute__((ext_vector_type(4)));
typedef float f32x4 __attribute__((ext_vector_type(4)));

#define GLD16(gp, lp) __builtin_amdgcn_global_load_lds((const __attribute__((address_space(1))) uint32_t*)(gp), (__attribute__((address_space(3))) uint32_t*)(lp), 16, 0, 0)

__device__ __forceinline__ float wredsum(float v){
  #pragma unroll
  for (int o=32;o;o>>=1) v += __shfl_down(v,o,64);
  return v;
}

// ---------------- transpose-convert fp32 [nmat][768][768] -> f16 [nmat][o][i] ----------------
__global__ __launch_bounds__(256) void kConvW(const float* __restrict__ w, f16* __restrict__ wT) {
  int bid = blockIdx.x;
  int ot = bid % 12; int it = (bid/12) % 12; int r = bid / 144;
  __shared__ float t[64*68];
  int tid = threadIdx.x;
  int ri = tid >> 2, c = tid & 3;
  const float* src = w + ((size_t)r*F_ + (it*64 + ri))*F_ + ot*64 + c*16;
  #pragma unroll
  for (int j=0;j<4;j++){
    f32x4 v4 = *(const f32x4*)(src + j*4);
    *(f32x4*)&t[ri*68 + c*16 + j*4] = v4;
  }
  __syncthreads();
  int ro = tid >> 2;
  f16 outv[16];
  #pragma unroll
  for (int j=0;j<16;j++) outv[j] = (f16)t[(c*16+j)*68 + ro];
  f16* dst = wT + ((size_t)r*F_ + (ot*64+ro))*F_ + it*64 + c*16;
  *(f16x8*)dst = *(f16x8*)&outv[0];
  *(f16x8*)(dst+8) = *(f16x8*)&outv[8];
}

// ---------------- v[r,i] = dot(w[r,i,:], sw) ; rows = 41*768, wave per row ----------------
__global__ __launch_bounds__(256) void kV(const float* __restrict__ w, const float* __restrict__ sw, float* __restrict__ v) {
  int idx = blockIdx.x*4 + (threadIdx.x>>6);
  int lane = threadIdx.x & 63;
  const float* row = w + (size_t)idx*F_ + lane*12;
  const float* swp = sw + lane*12;
  float acc = 0.f;
  #pragma unroll
  for (int j=0;j<3;j++){
    f32x4 a = *(const f32x4*)(row + j*4);
    f32x4 b = *(const f32x4*)(swp + j*4);
    acc += a.x*b.x + a.y*b.y + a.z*b.z + a.w*b.w;
  }
  acc = wredsum(acc);
  if (lane==0) v[idx] = acc;
}

// ---------------- transpose [b][s][f] (T=float or f16) -> f16 [b][f][s] ----------------
template<typename T>
__global__ __launch_bounds__(256) void kTransTo16T(const T* __restrict__ h, f16* __restrict__ hT) {
  int bid = blockIdx.x;
  int st = bid & 1; int ft = (bid>>1) % 12; int b = bid / 24;
  __shared__ f16 t[64*72];
  int tid = threadIdx.x;
  int sl = tid>>2, c = tid&3;
  const T* src = h + ((size_t)b*S_ + st*64 + sl)*F_ + ft*64 + c*16;
  f16 tmp[16];
  #pragma unroll
  for (int j=0;j<16;j++) tmp[j] = (f16)src[j];
  *(f16x8*)&t[sl*72 + c*16]     = *(f16x8*)&tmp[0];
  *(f16x8*)&t[sl*72 + c*16 + 8] = *(f16x8*)&tmp[8];
  __syncthreads();
  int fl = tid>>2;
  f16 outv[16];
  #pragma unroll
  for (int j=0;j<16;j++) outv[j] = t[(c*16+j)*72 + fl];
  f16* dst = hT + ((size_t)b*F_ + ft*64 + fl)*S_ + st*64 + c*16;
  *(f16x8*)dst = *(f16x8*)&outv[0];
  *(f16x8*)(dst+8) = *(f16x8*)&outv[8];
}

// ---------------- u[(b*R+r)*S+k] = dot(h[b,k,:], v[r,:]) ----------------
__global__ __launch_bounds__(256) void kU(const float* __restrict__ h, const float* __restrict__ v, float* __restrict__ u) {
  int idx = blockIdx.x*4 + (threadIdx.x>>6);
  int lane = threadIdx.x&63;
  int k = idx & 127;
  int br = idx >> 7;
  int r = br % R_;
  int b = br / R_;
  const float* hr = h + ((size_t)b*S_ + k)*F_ + lane*12;
  const float* vr = v + (size_t)r*F_ + lane*12;
  float acc=0.f;
  #pragma unroll
  for (int j=0;j<3;j++){
    f32x4 a = *(const f32x4*)(hr+j*4);
    f32x4 c4 = *(const f32x4*)(vr+j*4);
    acc += a.x*c4.x+a.y*c4.y+a.z*c4.z+a.w*c4.w;
  }
  acc = wredsum(acc);
  if (lane==0) u[idx] = acc;
}

// ---------------- denom + logits per (b,r,s) ----------------
__global__ __launch_bounds__(256) void kLogits(const float* __restrict__ adj, const float* __restrict__ u,
                        const float* __restrict__ sb_all, int l,
                        float* __restrict__ dinv, float* __restrict__ lg) {
  int idx = blockIdx.x*4 + (threadIdx.x>>6);   // (b*R+r)*S + s
  int lane = threadIdx.x&63;
  const float* arow = adj + (size_t)idx*S_;
  int br = idx >> 7;
  const float* up = u + (size_t)br*S_;
  float a0 = arow[lane], a1 = arow[lane+64];
  float u0 = up[lane],   u1 = up[lane+64];
  float ssum = a0+a1;
  float sdot = a0*u0 + a1*u1;
  ssum = wredsum(ssum);
  sdot = wredsum(sdot);
  if (lane==0){
    float dv = (ssum==0.0f) ? 1.0f : (1.0f/ssum);
    dinv[idx] = dv;
    lg[idx] = sdot*dv + sb_all[l];
  }
}

// ---------------- softmax over r (41) per (b,s) ----------------
__global__ __launch_bounds__(256) void kSoftmaxR(const float* __restrict__ lg, float* __restrict__ c) {
  int t = blockIdx.x*256 + threadIdx.x;  // 0..1023
  int b = t >> 7, s = t & 127;
  float vals[R_];
  float mx = -1e30f;
  #pragma unroll
  for (int r=0;r<R_;r++){ float x = lg[((size_t)b*R_+r)*S_ + s]; vals[r]=x; mx = fmaxf(mx,x); }
  float sum=0.f;
  #pragma unroll
  for (int r=0;r<R_;r++){ vals[r] = expf(vals[r]-mx); sum += vals[r]; }
  float inv = 1.0f/sum;
  #pragma unroll
  for (int r=0;r<R_;r++) c[((size_t)b*R_+r)*S_+s] = vals[r]*inv;
}

// ---------------- M16 = f16(SM * c * dinv * adj) ----------------
__global__ __launch_bounds__(256) void kM16(const float* __restrict__ adj, const float* __restrict__ c,
                     const float* __restrict__ dinv, f16* __restrict__ M) {
  int t = blockIdx.x*256 + threadIdx.x;
  int brs = t >> 5; int k4 = (t & 31) * 4;
  float a = SM_SCALE * c[brs] * dinv[brs];
  f32x4 v4 = *(const f32x4*)(adj + (size_t)brs*S_ + k4);
  f16x4 o;
  o[0]=(f16)(v4.x*a); o[1]=(f16)(v4.y*a); o[2]=(f16)(v4.z*a); o[3]=(f16)(v4.w*a);
  *(f16x4*)(M + (size_t)brs*S_ + k4) = o;
}

// ---------------- G[b,r] = M16[b,r] (128x128) @ h16T^T -> (128 x 64-col tile) ----------------
__global__ __launch_bounds__(256) void kGgemm(const f16* __restrict__ M, const f16* __restrict__ hT, f16* __restrict__ G) {
  __shared__ f16 lds[128*128 + 64*128];   // 48 KB
  f16* lsA = lds;              // [128 s][128 k]
  f16* lsB = lds + 16384;      // [64 i][128 k]
  int bid = blockIdx.x;
  int nt = bid % 12; int r = (bid/12) % R_; int b = bid/(12*R_);
  int tid = threadIdx.x, wid = tid>>6, lane = tid&63;
  const f16* Ab = M + (size_t)(b*R_ + r)*(S_*S_);
  const f16* Bb = hT + ((size_t)b*F_ + nt*64)*S_;
  #pragma unroll
  for (int j=0;j<8;j++){
    int qd = wid*8 + j;
    GLD16(Ab + qd*512 + lane*8, lsA + qd*512);
  }
  #pragma unroll
  for (int j=0;j<4;j++){
    int qd = wid*4 + j;
    GLD16(Bb + qd*512 + lane*8, lsB + qd*512);
  }
  __syncthreads();
  f32x4 acc[4][2] = {};
  int wr = wid>>1, wc = wid&1;
  int lr = lane&15, kk0 = (lane>>4)*8;
  #pragma unroll
  for (int ks=0;ks<4;ks++){
    int kk = ks*32 + kk0;
    f16x8 av[4], bv[2];
    #pragma unroll
    for (int i=0;i<4;i++) av[i] = *(const f16x8*)&lsA[(wr*64+i*16+lr)*128 + kk];
    #pragma unroll
    for (int i=0;i<2;i++) bv[i] = *(const f16x8*)&lsB[(wc*32+i*16+lr)*128 + kk];
    #pragma unroll
    for (int mi=0;mi<4;mi++)
      #pragma unroll
      for (int ni=0;ni<2;ni++)
        acc[mi][ni] = __builtin_amdgcn_mfma_f32_16x16x32_f16(av[mi],bv[ni],acc[mi][ni],0,0,0);
  }
  __syncthreads();
  // repack through LDS [128][80] then coalesced store
  #pragma unroll
  for (int mi=0;mi<4;mi++)
    #pragma unroll
    for (int ni=0;ni<2;ni++){
      int row = wr*64 + mi*16 + (lane>>4)*4;
      int col = wc*32 + ni*16 + lr;
      #pragma unroll
      for (int i=0;i<4;i++)
        lds[(row+i)*80 + col] = (f16)acc[mi][ni][i];
    }
  __syncthreads();
  int row = tid>>1, seg = tid&1;
  f16* dst = G + ((size_t)(b*R_ + r)*S_ + row)*F_ + nt*64 + seg*32;
  const f16* sl = lds + row*80 + seg*32;
  #pragma unroll
  for (int j=0;j<4;j++) *(f16x8*)(dst + j*8) = *(const f16x8*)(sl + j*8);
}

// ---------------- big GEMM: Cpart[g] = A''(1024 x K_g) @ W'(K_g x 768), split-K over r ----------------
__global__ __launch_bounds__(256) void kOutGemm(const f16* __restrict__ G, const f16* __restrict__ WT, float* __restrict__ Cp) {
  __shared__ f16 lsA[128*64];
  __shared__ f16 lsB[128*64];
  int bid = blockIdx.x;
  int g = bid % 12, nt = (bid/12) % 6, mt = bid/72;
  int r0 = (g<5)? g*4 : 20 + (g-5)*3;
  int nr = (g<5)? 4 : 3;
  int tid = threadIdx.x, wid = tid>>6, lane = tid&63;
  size_t abase[4], bbase[4];
  #pragma unroll
  for (int j=0;j<4;j++){
    int qd = wid*4 + j;
    int row = mt*128 + qd*8 + (lane>>3);
    int b = row >> 7, s = row & 127;
    abase[j] = ((size_t)b*R_*S_ + s)*F_ + (lane&7)*8;   // + r*S_*F_ + it*64
    int o = nt*128 + qd*8 + (lane>>3);
    bbase[j] = (size_t)o*F_ + (lane&7)*8;               // + r*F_*F_ + it*64
  }
  f32x4 acc[4][4] = {};
  int wr = wid>>1, wc = wid&1;
  int lr = lane&15, kk0 = (lane>>4)*8;
  for (int rr=0; rr<nr; ++rr){
    int r = r0 + rr;
    const f16* Ar = G  + (size_t)r*S_*F_;
    const f16* Br = WT + (size_t)r*F_*F_;
    for (int it=0; it<12; ++it){
      #pragma unroll
      for (int j=0;j<4;j++){
        int qd = wid*4+j;
        GLD16(Ar + abase[j] + it*64, lsA + qd*512);
        GLD16(Br + bbase[j] + it*64, lsB + qd*512);
      }
      __syncthreads();
      #pragma unroll
      for (int ks=0;ks<2;ks++){
        int kk = ks*32 + kk0;
        f16x8 av[4], bv[4];
        #pragma unroll
        for (int i=0;i<4;i++) av[i] = *(const f16x8*)&lsA[(wr*64+i*16+lr)*64 + kk];
        #pragma unroll
        for (int i=0;i<4;i++) bv[i] = *(const f16x8*)&lsB[(wc*64+i*16+lr)*64 + kk];
        #pragma unroll
        for (int mi=0;mi<4;mi++)
          #pragma unroll
          for (int ni=0;ni<4;ni++)
            acc[mi][ni] = __builtin_amdgcn_mfma_f32_16x16x32_f16(av[mi],bv[ni],acc[mi][ni],0,0,0);
      }
      __syncthreads();
    }
  }
  #pragma unroll
  for (int mi=0;mi<4;mi++)
    #pragma unroll
    for (int ni=0;ni<4;ni++){
      int row = mt*128 + wr*64 + mi*16 + (lane>>4)*4;
      int col = nt*128 + wc*64 + ni*16 + lr;
      #pragma unroll
      for (int i=0;i<4;i++)
        Cp[((size_t)g*BS_ + row + i)*F_ + col] = acc[mi][ni][i];
    }
}

// ---------------- reduce split-K partials, /SM, relu, write h32 + h16 ----------------
__global__ __launch_bounds__(256) void kReduce(const float* __restrict__ Cp, float* __restrict__ h32, f16* __restrict__ h16o) {
  int t = blockIdx.x*256 + threadIdx.x;
  size_t i4 = (size_t)t*4;
  f32x4 s = {};
  #pragma unroll
  for (int g=0; g<12; g++){
    f32x4 v4 = *(const f32x4*)(Cp + (size_t)g*BS_*F_ + i4);
    s.x += v4.x; s.y += v4.y; s.z += v4.z; s.w += v4.w;
  }
  const float inv = 1.0f/SM_SCALE;
  f32x4 rr;
  rr.x = fmaxf(s.x*inv, 0.f); rr.y = fmaxf(s.y*inv, 0.f);
  rr.z = fmaxf(s.z*inv, 0.f); rr.w = fmaxf(s.w*inv, 0.f);
  *(f32x4*)(h32 + i4) = rr;
  f16x4 o; o[0]=(f16)rr.x; o[1]=(f16)rr.y; o[2]=(f16)rr.z; o[3]=(f16)rr.w;
  *(f16x4*)(h16o + i4) = o;
}

// ---------------- kx = h2 @ wk + bk  (1024x768x768, MFMA) ----------------
__global__ __launch_bounds__(256) void kKx(const f16* __restrict__ A, const f16* __restrict__ BT,
                    const float* __restrict__ bias, float* __restrict__ C) {
  __shared__ f16 lsA[128*64];
  __shared__ f16 lsB[128*64];
  int bid = blockIdx.x;
  int nt = bid % 6, mt = bid / 6;
  int tid = threadIdx.x, wid = tid>>6, lane = tid&63;
  size_t abase[4], bbase[4];
  #pragma unroll
  for (int j=0;j<4;j++){
    int qd = wid*4 + j;
    int row = mt*128 + qd*8 + (lane>>3);
    abase[j] = (size_t)row*F_ + (lane&7)*8;
    int o = nt*128 + qd*8 + (lane>>3);
    bbase[j] = (size_t)o*F_ + (lane&7)*8;
  }
  f32x4 acc[4][4] = {};
  int wr = wid>>1, wc = wid&1;
  int lr = lane&15, kk0 = (lane>>4)*8;
  for (int it=0; it<12; ++it){
    #pragma unroll
    for (int j=0;j<4;j++){
      int qd = wid*4+j;
      GLD16(A + abase[j] + it*64, lsA + qd*512);
      GLD16(BT + bbase[j] + it*64, lsB + qd*512);
    }
    __syncthreads();
    #pragma unroll
    for (int ks=0;ks<2;ks++){
      int kk = ks*32 + kk0;
      f16x8 av[4], bv[4];
      #pragma unroll
      for (int i=0;i<4;i++) av[i] = *(const f16x8*)&lsA[(wr*64+i*16+lr)*64 + kk];
      #pragma unroll
      for (int i=0;i<4;i++) bv[i] = *(const f16x8*)&lsB[(wc*64+i*16+lr)*64 + kk];
      #pragma unroll
      for (int mi=0;mi<4;mi++)
        #pragma unroll
        for (int ni=0;ni<4;ni++)
          acc[mi][ni] = __builtin_amdgcn_mfma_f32_16x16x32_f16(av[mi],bv[ni],acc[mi][ni],0,0,0);
    }
    __syncthreads();
  }
  #pragma unroll
  for (int mi=0;mi<4;mi++)
    #pragma unroll
    for (int ni=0;ni<4;ni++){
      int row = mt*128 + wr*64 + mi*16 + (lane>>4)*4;
      int col = nt*128 + wc*64 + ni*16 + lr;
      float bb = bias[col];
      #pragma unroll
      for (int i=0;i<4;i++)
        C[(size_t)(row+i)*F_ + col] = acc[mi][ni][i] + bb;
    }
}

// ---------------- attention core per (b,h): qx, qw, score, softmax, o ----------------
__global__ __launch_bounds__(256) void kAttn(const float* __restrict__ kx, const float* __restrict__ qin,
                      const float* __restrict__ wq, const float* __restrict__ bq,
                      const float* __restrict__ wbil, float* __restrict__ obuf) {
  int bid = blockIdx.x; int h = bid & 7; int b = bid >> 3;
  __shared__ float qx[HID_], qw[HID_], sc[S_];
  __shared__ float smax, ssum;
  int t = threadIdx.x;
  if (t < HID_) {
    float acc=0.f;
    const float* qp = qin + (size_t)b*F_;
    const float* wp = wq + h*HID_ + t;
    for (int i=0;i<F_;i++) acc += qp[i]*wp[(size_t)i*F_];
    qx[t] = acc + bq[h*HID_+t];
  }
  __syncthreads();
  if (t < HID_) {
    float acc=0.f;
    for (int e=0;e<HID_;e++) acc += qx[e]*wbil[e*HID_+t];
    qw[t] = acc;
  }
  __syncthreads();
  if (t < S_) {
    float acc=0.f;
    const float* kp = kx + ((size_t)b*S_ + t)*F_ + h*HID_;
    for (int e=0;e<HID_;e++) acc += qw[e]*kp[e];
    sc[t] = acc;
  }
  __syncthreads();
  if (t==0){ float m=-1e30f; for(int k=0;k<S_;k++) m=fmaxf(m,sc[k]); smax=m; }
  __syncthreads();
  if (t < S_) sc[t] = expf(sc[t]-smax);
  __syncthreads();
  if (t==0){ float s=0.f; for(int k=0;k<S_;k++) s+=sc[k]; ssum=s; }
  __syncthreads();
  if (t < HID_) {
    float acc=0.f;
    const float* kp = kx + ((size_t)b*S_)*F_ + h*HID_ + t;
    for (int k=0;k<S_;k++) acc += sc[k]*kp[(size_t)k*F_];
    obuf[(size_t)b*F_ + h*HID_ + t] = acc/ssum;
  }
}

// ---------------- final projection out = o @ wproj + bproj ----------------
__global__ __launch_bounds__(256) void kProj(const float* __restrict__ obuf, const float* __restrict__ wproj,
                      const float* __restrict__ bproj, float* __restrict__ outp) {
  int b = blockIdx.x; int t = threadIdx.x;
  __shared__ float ov[F_];
  for (int j=t;j<F_;j+=256) ov[j] = obuf[(size_t)b*F_ + j];
  __syncthreads();
  float a0=bproj[t], a1=bproj[t+256], a2=bproj[t+512];
  for (int j=0;j<F_;j++){
    float o_ = ov[j];
    const float* wr_ = wproj + (size_t)j*F_;
    a0 += o_*wr_[t]; a1 += o_*wr_[t+256]; a2 += o_*wr_[t+512];
  }
  outp[(size_t)b*F_ + t]       = a0;
  outp[(size_t)b*F_ + t + 256] = a1;
  outp[(size_t)b*F_ + t + 512] = a2;
}

extern "C" void kernel_launch(void* const* d_in, const int* in_sizes, int n_in,
                              void* d_out, int out_size, void* d_ws, size_t ws_size,
                              hipStream_t stream) {
  (void)in_sizes; (void)n_in; (void)out_size;
  const float* x      = (const float*)d_in[0];
  const float* adj    = (const float*)d_in[1];
  const float* qin    = (const float*)d_in[2];
  const float* w_rgcn = (const float*)d_in[3];
  const float* score_w= (const float*)d_in[4];
  const float* score_b= (const float*)d_in[5];
  const float* wk     = (const float*)d_in[6];
  const float* bk     = (const float*)d_in[7];
  const float* wq     = (const float*)d_in[8];
  const float* bq     = (const float*)d_in[9];
  const float* wbil   = (const float*)d_in[10];
  const float* wproj  = (const float*)d_in[11];
  const float* bproj  = (const float*)d_in[12];
  float* outp = (float*)d_out;

  char* p = (char*)d_ws;
  auto alloc = [&](size_t bytes)->char* {
    char* r = p; p += (bytes + 255) & ~(size_t)255; return r;
  };
  f16*   w16T  = (f16*)  alloc((size_t)R_*F_*F_*2);
  f16*   G16   = (f16*)  alloc((size_t)B_*R_*S_*F_*2);
  f16*   M16   = (f16*)  alloc((size_t)B_*R_*S_*S_*2);
  float* Cpart = (float*)alloc((size_t)12*BS_*F_*4);
  float* h32a  = (float*)alloc((size_t)BS_*F_*4);
  float* h32b  = (float*)alloc((size_t)BS_*F_*4);
  f16*   h16row= (f16*)  alloc((size_t)BS_*F_*2);
  f16*   h16T  = (f16*)  alloc((size_t)BS_*F_*2);
  float* kx    = (float*)alloc((size_t)BS_*F_*4);
  f16*   wkT   = (f16*)  alloc((size_t)F_*F_*2);
  float* vbuf  = (float*)alloc((size_t)R_*F_*4);
  float* ubuf  = (float*)alloc((size_t)B_*R_*S_*4);
  float* dinv  = (float*)alloc((size_t)B_*R_*S_*4);
  float* lgb   = (float*)alloc((size_t)B_*R_*S_*4);
  float* cbuf  = (float*)alloc((size_t)B_*R_*S_*4);
  float* obuf  = (float*)alloc((size_t)B_*F_*4);
  if ((size_t)(p - (char*)d_ws) > ws_size) return;  // workspace insufficient -> fail loudly

  const size_t WL = (size_t)R_*F_*F_;   // w_rgcn layer stride

  // ---- layer 0 (h = x) ----
  kConvW<<<R_*144, 256, 0, stream>>>(w_rgcn, w16T);
  kV<<<7872, 256, 0, stream>>>(w_rgcn, score_w, vbuf);
  kTransTo16T<float><<<192, 256, 0, stream>>>(x, h16T);
  kU<<<10496, 256, 0, stream>>>(x, vbuf, ubuf);
  kLogits<<<10496, 256, 0, stream>>>(adj, ubuf, score_b, 0, dinv, lgb);
  kSoftmaxR<<<4, 256, 0, stream>>>(lgb, cbuf);
  kM16<<<5248, 256, 0, stream>>>(adj, cbuf, dinv, M16);
  kGgemm<<<B_*R_*12, 256, 0, stream>>>(M16, h16T, G16);
  kOutGemm<<<576, 256, 0, stream>>>(G16, w16T, Cpart);
  kReduce<<<768, 256, 0, stream>>>(Cpart, h32a, h16row);
  kTransTo16T<f16><<<192, 256, 0, stream>>>(h16row, h16T);

  // ---- layer 1 (h = h32a) ----
  kConvW<<<R_*144, 256, 0, stream>>>(w_rgcn + WL, w16T);
  kV<<<7872, 256, 0, stream>>>(w_rgcn + WL, score_w + F_, vbuf);
  kU<<<10496, 256, 0, stream>>>(h32a, vbuf, ubuf);
  kLogits<<<10496, 256, 0, stream>>>(adj, ubuf, score_b, 1, dinv, lgb);
  kSoftmaxR<<<4, 256, 0, stream>>>(lgb, cbuf);
  kM16<<<5248, 256, 0, stream>>>(adj, cbuf, dinv, M16);
  kGgemm<<<B_*R_*12, 256, 0, stream>>>(M16, h16T, G16);
  kOutGemm<<<576, 256, 0, stream>>>(G16, w16T, Cpart);
  kReduce<<<768, 256, 0, stream>>>(Cpart, h32b, h16row);

  // ---- attention ----
  kConvW<<<144, 256, 0, stream>>>(wk, wkT);
  kKx<<<48, 256, 0, stream>>>(h16row, wkT, bk, kx);
  kAttn<<<64, 256, 0, stream>>>(kx, qin, wq, bq, wbil, obuf);
  kProj<<<8, 256, 0, stream>>>(obuf, wproj, bproj, outp);
}

// Round 2
// 530.399 us; speedup vs baseline: 1.0835x; 1.0835x over previous
//
#include <hip/hip_runtime.h>
#include <stdint.h>

#define B_ 8
#define S_ 128
#define R_ 41
#define F_ 768
#define NH_ 8
#define HID_ 96
#define BS_ (B_*S_)
#define SM_SCALE 256.0f

typedef _Float16 f16;
typedef _Float16 f16x8 __attribute__((ext_vector_type(8)));
typedef _Float16 f16x4 __attribute__((ext_vector_type(4)));
typedef float f32x4 __attribute__((ext_vector_type(4)));

#define GLD16(gp, lp) __builtin_amdgcn_global_load_lds((const __attribute__((address_space(1))) uint32_t*)(gp), (__attribute__((address_space(3))) uint32_t*)(lp), 16, 0, 0)

__device__ __forceinline__ float wredsum(float v){
  #pragma unroll
  for (int o=32;o;o>>=1) v += __shfl_down(v,o,64);
  return v;
}

// ---------------- fused: transpose-convert w_rgcn layer -> f16 [r][o][i]  AND  v[r,i]=dot(w[r,i,:],sw) ----------------
// block = (r, it): 64 i-rows, loops all 12 ot chunks. Saves kV's full re-read of w.
__global__ __launch_bounds__(256) void kConvWV(const float* __restrict__ w, const float* __restrict__ sw,
                                               f16* __restrict__ wT, float* __restrict__ v) {
  int bid = blockIdx.x;
  int it = bid % 12, r = bid / 12;
  __shared__ float t[64*68];
  int tid = threadIdx.x;
  int ri = tid >> 2, c = tid & 3;
  float vacc = 0.f;
  for (int ot = 0; ot < 12; ++ot) {
    const float* src = w + ((size_t)r*F_ + (it*64 + ri))*F_ + ot*64 + c*16;
    const float* swp = sw + ot*64 + c*16;
    __syncthreads();   // previous iteration's reads done before overwrite
    #pragma unroll
    for (int j=0;j<4;j++){
      f32x4 v4 = *(const f32x4*)(src + j*4);
      f32x4 s4 = *(const f32x4*)(swp + j*4);
      vacc += v4.x*s4.x + v4.y*s4.y + v4.z*s4.z + v4.w*s4.w;
      *(f32x4*)&t[ri*68 + c*16 + j*4] = v4;
    }
    __syncthreads();
    int ro = tid >> 2;
    f16 outv[16];
    #pragma unroll
    for (int j=0;j<16;j++) outv[j] = (f16)t[(c*16+j)*68 + ro];
    f16* dst = wT + ((size_t)r*F_ + (ot*64+ro))*F_ + it*64 + c*16;
    *(f16x8*)dst = *(f16x8*)&outv[0];
    *(f16x8*)(dst+8) = *(f16x8*)&outv[8];
  }
  // reduce vacc over the 4 c-threads (adjacent lanes: tid = ri*4 + c)
  vacc += __shfl_down(vacc, 1, 64);
  vacc += __shfl_down(vacc, 2, 64);
  if (c == 0) v[(size_t)r*F_ + it*64 + ri] = vacc;
}

// ---------------- transpose-convert fp32 [768][768] -> f16 [o][i] (for wk) ----------------
__global__ __launch_bounds__(256) void kConvW(const float* __restrict__ w, f16* __restrict__ wT) {
  int bid = blockIdx.x;
  int ot = bid % 12; int it = (bid/12) % 12; int r = bid / 144;
  __shared__ float t[64*68];
  int tid = threadIdx.x;
  int ri = tid >> 2, c = tid & 3;
  const float* src = w + ((size_t)r*F_ + (it*64 + ri))*F_ + ot*64 + c*16;
  #pragma unroll
  for (int j=0;j<4;j++){
    f32x4 v4 = *(const f32x4*)(src + j*4);
    *(f32x4*)&t[ri*68 + c*16 + j*4] = v4;
  }
  __syncthreads();
  int ro = tid >> 2;
  f16 outv[16];
  #pragma unroll
  for (int j=0;j<16;j++) outv[j] = (f16)t[(c*16+j)*68 + ro];
  f16* dst = wT + ((size_t)r*F_ + (ot*64+ro))*F_ + it*64 + c*16;
  *(f16x8*)dst = *(f16x8*)&outv[0];
  *(f16x8*)(dst+8) = *(f16x8*)&outv[8];
}

// ---------------- transpose [b][s][f] (T=float or f16) -> f16 [b][f][s] ----------------
template<typename T>
__global__ __launch_bounds__(256) void kTransTo16T(const T* __restrict__ h, f16* __restrict__ hT) {
  int bid = blockIdx.x;
  int st = bid & 1; int ft = (bid>>1) % 12; int b = bid / 24;
  __shared__ f16 t[64*72];
  int tid = threadIdx.x;
  int sl = tid>>2, c = tid&3;
  const T* src = h + ((size_t)b*S_ + st*64 + sl)*F_ + ft*64 + c*16;
  f16 tmp[16];
  #pragma unroll
  for (int j=0;j<16;j++) tmp[j] = (f16)src[j];
  *(f16x8*)&t[sl*72 + c*16]     = *(f16x8*)&tmp[0];
  *(f16x8*)&t[sl*72 + c*16 + 8] = *(f16x8*)&tmp[8];
  __syncthreads();
  int fl = tid>>2;
  f16 outv[16];
  #pragma unroll
  for (int j=0;j<16;j++) outv[j] = t[(c*16+j)*72 + fl];
  f16* dst = hT + ((size_t)b*F_ + ft*64 + fl)*S_ + st*64 + c*16;
  *(f16x8*)dst = *(f16x8*)&outv[0];
  *(f16x8*)(dst+8) = *(f16x8*)&outv[8];
}

// ---------------- u[(b*R+r)*S+k] = dot(h[b,k,:], v[r,:]) ----------------
__global__ __launch_bounds__(256) void kU(const float* __restrict__ h, const float* __restrict__ v, float* __restrict__ u) {
  int idx = blockIdx.x*4 + (threadIdx.x>>6);
  int lane = threadIdx.x&63;
  int k = idx & 127;
  int br = idx >> 7;
  int r = br % R_;
  int b = br / R_;
  const float* hr = h + ((size_t)b*S_ + k)*F_ + lane*12;
  const float* vr = v + (size_t)r*F_ + lane*12;
  float acc=0.f;
  #pragma unroll
  for (int j=0;j<3;j++){
    f32x4 a = *(const f32x4*)(hr+j*4);
    f32x4 c4 = *(const f32x4*)(vr+j*4);
    acc += a.x*c4.x+a.y*c4.y+a.z*c4.z+a.w*c4.w;
  }
  acc = wredsum(acc);
  if (lane==0) u[idx] = acc;
}

// ---------------- denom + logits per (b,r,s) ----------------
__global__ __launch_bounds__(256) void kLogits(const float* __restrict__ adj, const float* __restrict__ u,
                        const float* __restrict__ sb_all, int l,
                        float* __restrict__ dinv, float* __restrict__ lg) {
  int idx = blockIdx.x*4 + (threadIdx.x>>6);   // (b*R+r)*S + s
  int lane = threadIdx.x&63;
  const float* arow = adj + (size_t)idx*S_;
  int br = idx >> 7;
  const float* up = u + (size_t)br*S_;
  float a0 = arow[lane], a1 = arow[lane+64];
  float u0 = up[lane],   u1 = up[lane+64];
  float ssum = a0+a1;
  float sdot = a0*u0 + a1*u1;
  ssum = wredsum(ssum);
  sdot = wredsum(sdot);
  if (lane==0){
    float dv = (ssum==0.0f) ? 1.0f : (1.0f/ssum);
    dinv[idx] = dv;
    lg[idx] = sdot*dv + sb_all[l];
  }
}

// ---------------- softmax over r (41) per (b,s) ----------------
__global__ __launch_bounds__(256) void kSoftmaxR(const float* __restrict__ lg, float* __restrict__ c) {
  int t = blockIdx.x*256 + threadIdx.x;  // 0..1023
  int b = t >> 7, s = t & 127;
  float vals[R_];
  float mx = -1e30f;
  #pragma unroll
  for (int r=0;r<R_;r++){ float x = lg[((size_t)b*R_+r)*S_ + s]; vals[r]=x; mx = fmaxf(mx,x); }
  float sum=0.f;
  #pragma unroll
  for (int r=0;r<R_;r++){ vals[r] = expf(vals[r]-mx); sum += vals[r]; }
  float inv = 1.0f/sum;
  #pragma unroll
  for (int r=0;r<R_;r++) c[((size_t)b*R_+r)*S_+s] = vals[r]*inv;
}

// ---------------- M16 = f16(SM * c * dinv * adj) ----------------
__global__ __launch_bounds__(256) void kM16(const float* __restrict__ adj, const float* __restrict__ c,
                     const float* __restrict__ dinv, f16* __restrict__ M) {
  int t = blockIdx.x*256 + threadIdx.x;
  int brs = t >> 5; int k4 = (t & 31) * 4;
  float a = SM_SCALE * c[brs] * dinv[brs];
  f32x4 v4 = *(const f32x4*)(adj + (size_t)brs*S_ + k4);
  f16x4 o;
  o[0]=(f16)(v4.x*a); o[1]=(f16)(v4.y*a); o[2]=(f16)(v4.z*a); o[3]=(f16)(v4.w*a);
  *(f16x4*)(M + (size_t)brs*S_ + k4) = o;
}

// ---------------- G[b,r] = M16[b,r] (128x128) @ h16T^T -> 128x128 col tile ----------------
__global__ __launch_bounds__(256) void kGgemm(const f16* __restrict__ M, const f16* __restrict__ hT, f16* __restrict__ G) {
  __shared__ f16 lds[2*16384];   // 64 KB
  f16* lsA = lds;              // [128 s][128 k]
  f16* lsB = lds + 16384;      // [128 i][128 k]
  int bid = blockIdx.x;
  int nt = bid % 6; int r = (bid/6) % R_; int b = bid/(6*R_);
  int tid = threadIdx.x, wid = tid>>6, lane = tid&63;
  const f16* Ab = M + (size_t)(b*R_ + r)*(S_*S_);
  const f16* Bb = hT + ((size_t)b*F_ + nt*128)*S_;
  #pragma unroll
  for (int j=0;j<8;j++){
    int qd = wid*8 + j;
    GLD16(Ab + qd*512 + lane*8, lsA + qd*512);
    GLD16(Bb + qd*512 + lane*8, lsB + qd*512);
  }
  __syncthreads();
  f32x4 acc[4][4] = {};
  int wr = wid>>1, wc = wid&1;
  int lr = lane&15, kk0 = (lane>>4)*8;
  #pragma unroll
  for (int ks=0;ks<4;ks++){
    int kk = ks*32 + kk0;
    f16x8 av[4], bv[4];
    #pragma unroll
    for (int i=0;i<4;i++) av[i] = *(const f16x8*)&lsA[(wr*64+i*16+lr)*128 + kk];
    #pragma unroll
    for (int i=0;i<4;i++) bv[i] = *(const f16x8*)&lsB[(wc*64+i*16+lr)*128 + kk];
    #pragma unroll
    for (int mi=0;mi<4;mi++)
      #pragma unroll
      for (int ni=0;ni<4;ni++)
        acc[mi][ni] = __builtin_amdgcn_mfma_f32_16x16x32_f16(av[mi],bv[ni],acc[mi][ni],0,0,0);
  }
  __syncthreads();
  // repack through LDS [128][136] then coalesced store of 128-col tile
  #pragma unroll
  for (int mi=0;mi<4;mi++)
    #pragma unroll
    for (int ni=0;ni<4;ni++){
      int row = wr*64 + mi*16 + (lane>>4)*4;
      int col = wc*64 + ni*16 + lr;
      #pragma unroll
      for (int i=0;i<4;i++)
        lds[(row+i)*136 + col] = (f16)acc[mi][ni][i];
    }
  __syncthreads();
  int row = tid>>1, seg = tid&1;
  f16* dst = G + ((size_t)(b*R_ + r)*S_ + row)*F_ + nt*128 + seg*64;
  const f16* sl = lds + row*136 + seg*64;
  #pragma unroll
  for (int j=0;j<8;j++) *(f16x8*)(dst + j*8) = *(const f16x8*)(sl + j*8);
}

// ---------------- big GEMM: Cpart[g] = A''(1024 x K_g) @ W'(K_g x 768), split-K over r ----------------
__global__ __launch_bounds__(256) void kOutGemm(const f16* __restrict__ G, const f16* __restrict__ WT, float* __restrict__ Cp) {
  __shared__ f16 lsA[128*64];
  __shared__ f16 lsB[128*64];
  int bid = blockIdx.x;
  int nt = bid % 6, g = (bid/6) % 12, mt = bid/72;   // nt fastest: consecutive blocks share A tile
  int r0 = (g<5)? g*4 : 20 + (g-5)*3;
  int nr = (g<5)? 4 : 3;
  int tid = threadIdx.x, wid = tid>>6, lane = tid&63;
  size_t abase[4], bbase[4];
  #pragma unroll
  for (int j=0;j<4;j++){
    int qd = wid*4 + j;
    int row = mt*128 + qd*8 + (lane>>3);
    int b = row >> 7, s = row & 127;
    abase[j] = ((size_t)b*R_*S_ + s)*F_ + (lane&7)*8;   // + r*S_*F_ + it*64
    int o = nt*128 + qd*8 + (lane>>3);
    bbase[j] = (size_t)o*F_ + (lane&7)*8;               // + r*F_*F_ + it*64
  }
  f32x4 acc[4][4] = {};
  int wr = wid>>1, wc = wid&1;
  int lr = lane&15, kk0 = (lane>>4)*8;
  for (int rr=0; rr<nr; ++rr){
    int r = r0 + rr;
    const f16* Ar = G  + (size_t)r*S_*F_;
    const f16* Br = WT + (size_t)r*F_*F_;
    for (int it=0; it<12; ++it){
      #pragma unroll
      for (int j=0;j<4;j++){
        int qd = wid*4+j;
        GLD16(Ar + abase[j] + it*64, lsA + qd*512);
        GLD16(Br + bbase[j] + it*64, lsB + qd*512);
      }
      __syncthreads();
      #pragma unroll
      for (int ks=0;ks<2;ks++){
        int kk = ks*32 + kk0;
        f16x8 av[4], bv[4];
        #pragma unroll
        for (int i=0;i<4;i++) av[i] = *(const f16x8*)&lsA[(wr*64+i*16+lr)*64 + kk];
        #pragma unroll
        for (int i=0;i<4;i++) bv[i] = *(const f16x8*)&lsB[(wc*64+i*16+lr)*64 + kk];
        #pragma unroll
        for (int mi=0;mi<4;mi++)
          #pragma unroll
          for (int ni=0;ni<4;ni++)
            acc[mi][ni] = __builtin_amdgcn_mfma_f32_16x16x32_f16(av[mi],bv[ni],acc[mi][ni],0,0,0);
      }
      __syncthreads();
    }
  }
  #pragma unroll
  for (int mi=0;mi<4;mi++)
    #pragma unroll
    for (int ni=0;ni<4;ni++){
      int row = mt*128 + wr*64 + mi*16 + (lane>>4)*4;
      int col = nt*128 + wc*64 + ni*16 + lr;
      #pragma unroll
      for (int i=0;i<4;i++)
        Cp[((size_t)g*BS_ + row + i)*F_ + col] = acc[mi][ni][i];
    }
}

// ---------------- reduce split-K partials, /SM, relu, write h32 + h16 ----------------
__global__ __launch_bounds__(256) void kReduce(const float* __restrict__ Cp, float* __restrict__ h32, f16* __restrict__ h16o) {
  int t = blockIdx.x*256 + threadIdx.x;
  size_t i4 = (size_t)t*4;
  f32x4 s = {};
  #pragma unroll
  for (int g=0; g<12; g++){
    f32x4 v4 = *(const f32x4*)(Cp + (size_t)g*BS_*F_ + i4);
    s.x += v4.x; s.y += v4.y; s.z += v4.z; s.w += v4.w;
  }
  const float inv = 1.0f/SM_SCALE;
  f32x4 rr;
  rr.x = fmaxf(s.x*inv, 0.f); rr.y = fmaxf(s.y*inv, 0.f);
  rr.z = fmaxf(s.z*inv, 0.f); rr.w = fmaxf(s.w*inv, 0.f);
  *(f32x4*)(h32 + i4) = rr;
  f16x4 o; o[0]=(f16)rr.x; o[1]=(f16)rr.y; o[2]=(f16)rr.z; o[3]=(f16)rr.w;
  *(f16x4*)(h16o + i4) = o;
}

// ---------------- kx = h2 @ wk + bk  (1024x768x768, MFMA) ----------------
__global__ __launch_bounds__(256) void kKx(const f16* __restrict__ A, const f16* __restrict__ BT,
                    const float* __restrict__ bias, float* __restrict__ C) {
  __shared__ f16 lsA[128*64];
  __shared__ f16 lsB[128*64];
  int bid = blockIdx.x;
  int nt = bid % 6, mt = bid / 6;
  int tid = threadIdx.x, wid = tid>>6, lane = tid&63;
  size_t abase[4], bbase[4];
  #pragma unroll
  for (int j=0;j<4;j++){
    int qd = wid*4 + j;
    int row = mt*128 + qd*8 + (lane>>3);
    abase[j] = (size_t)row*F_ + (lane&7)*8;
    int o = nt*128 + qd*8 + (lane>>3);
    bbase[j] = (size_t)o*F_ + (lane&7)*8;
  }
  f32x4 acc[4][4] = {};
  int wr = wid>>1, wc = wid&1;
  int lr = lane&15, kk0 = (lane>>4)*8;
  for (int it=0; it<12; ++it){
    #pragma unroll
    for (int j=0;j<4;j++){
      int qd = wid*4+j;
      GLD16(A + abase[j] + it*64, lsA + qd*512);
      GLD16(BT + bbase[j] + it*64, lsB + qd*512);
    }
    __syncthreads();
    #pragma unroll
    for (int ks=0;ks<2;ks++){
      int kk = ks*32 + kk0;
      f16x8 av[4], bv[4];
      #pragma unroll
      for (int i=0;i<4;i++) av[i] = *(const f16x8*)&lsA[(wr*64+i*16+lr)*64 + kk];
      #pragma unroll
      for (int i=0;i<4;i++) bv[i] = *(const f16x8*)&lsB[(wc*64+i*16+lr)*64 + kk];
      #pragma unroll
      for (int mi=0;mi<4;mi++)
        #pragma unroll
        for (int ni=0;ni<4;ni++)
          acc[mi][ni] = __builtin_amdgcn_mfma_f32_16x16x32_f16(av[mi],bv[ni],acc[mi][ni],0,0,0);
    }
    __syncthreads();
  }
  #pragma unroll
  for (int mi=0;mi<4;mi++)
    #pragma unroll
    for (int ni=0;ni<4;ni++){
      int row = mt*128 + wr*64 + mi*16 + (lane>>4)*4;
      int col = nt*128 + wc*64 + ni*16 + lr;
      float bb = bias[col];
      #pragma unroll
      for (int i=0;i<4;i++)
        C[(size_t)(row+i)*F_ + col] = acc[mi][ni][i] + bb;
    }
}

// ---------------- attention core per (b,h): qx, qw, score, softmax, o ----------------
__global__ __launch_bounds__(256) void kAttn(const float* __restrict__ kx, const float* __restrict__ qin,
                      const float* __restrict__ wq, const float* __restrict__ bq,
                      const float* __restrict__ wbil, float* __restrict__ obuf) {
  int bid = blockIdx.x; int h = bid & 7; int b = bid >> 3;
  __shared__ float qx[HID_], qw[HID_], sc[S_];
  __shared__ float smax, ssum;
  int t = threadIdx.x;
  if (t < HID_) {
    float a0=0.f,a1=0.f,a2=0.f,a3=0.f;
    const float* qp = qin + (size_t)b*F_;
    const float* wp = wq + h*HID_ + t;
    for (int i=0;i<F_;i+=4){
      a0 += qp[i]*wp[(size_t)i*F_];
      a1 += qp[i+1]*wp[(size_t)(i+1)*F_];
      a2 += qp[i+2]*wp[(size_t)(i+2)*F_];
      a3 += qp[i+3]*wp[(size_t)(i+3)*F_];
    }
    qx[t] = a0+a1+a2+a3 + bq[h*HID_+t];
  }
  __syncthreads();
  if (t < HID_) {
    float a0=0.f,a1=0.f;
    for (int e=0;e<HID_;e+=2){ a0 += qx[e]*wbil[e*HID_+t]; a1 += qx[e+1]*wbil[(e+1)*HID_+t]; }
    qw[t] = a0+a1;
  }
  __syncthreads();
  if (t < S_) {
    float a0=0.f,a1=0.f;
    const float* kp = kx + ((size_t)b*S_ + t)*F_ + h*HID_;
    for (int e=0;e<HID_;e+=2){ a0 += qw[e]*kp[e]; a1 += qw[e+1]*kp[e+1]; }
    sc[t] = a0+a1;
  }
  __syncthreads();
  if (t < 64) {
    float m = fmaxf(sc[t], sc[t+64]);
    #pragma unroll
    for (int o=32;o;o>>=1) m = fmaxf(m, __shfl_down(m,o,64));
    if (t==0) smax = m;
  }
  __syncthreads();
  if (t < S_) sc[t] = expf(sc[t]-smax);
  __syncthreads();
  if (t < 64) {
    float s = sc[t] + sc[t+64];
    s = wredsum(s);
    if (t==0) ssum = s;
  }
  __syncthreads();
  if (t < HID_) {
    float a0=0.f,a1=0.f;
    const float* kp = kx + ((size_t)b*S_)*F_ + h*HID_ + t;
    for (int k=0;k<S_;k+=2){ a0 += sc[k]*kp[(size_t)k*F_]; a1 += sc[k+1]*kp[(size_t)(k+1)*F_]; }
    obuf[(size_t)b*F_ + h*HID_ + t] = (a0+a1)/ssum;
  }
}

// ---------------- final projection out = o @ wproj + bproj ----------------
__global__ __launch_bounds__(256) void kProj(const float* __restrict__ obuf, const float* __restrict__ wproj,
                      const float* __restrict__ bproj, float* __restrict__ outp) {
  int bid = blockIdx.x; int b = bid/3, seg = bid%3;
  int t = threadIdx.x;
  __shared__ float ov[F_];
  for (int j=t;j<F_;j+=256) ov[j] = obuf[(size_t)b*F_ + j];
  __syncthreads();
  int col = seg*256 + t;
  float a0=0.f,a1=0.f,a2=0.f,a3=0.f;
  for (int j=0;j<F_;j+=4){
    a0 += ov[j]*wproj[(size_t)j*F_+col];
    a1 += ov[j+1]*wproj[(size_t)(j+1)*F_+col];
    a2 += ov[j+2]*wproj[(size_t)(j+2)*F_+col];
    a3 += ov[j+3]*wproj[(size_t)(j+3)*F_+col];
  }
  outp[(size_t)b*F_ + col] = bproj[col] + a0+a1+a2+a3;
}

extern "C" void kernel_launch(void* const* d_in, const int* in_sizes, int n_in,
                              void* d_out, int out_size, void* d_ws, size_t ws_size,
                              hipStream_t stream) {
  (void)in_sizes; (void)n_in; (void)out_size;
  const float* x      = (const float*)d_in[0];
  const float* adj    = (const float*)d_in[1];
  const float* qin    = (const float*)d_in[2];
  const float* w_rgcn = (const float*)d_in[3];
  const float* score_w= (const float*)d_in[4];
  const float* score_b= (const float*)d_in[5];
  const float* wk     = (const float*)d_in[6];
  const float* bk     = (const float*)d_in[7];
  const float* wq     = (const float*)d_in[8];
  const float* bq     = (const float*)d_in[9];
  const float* wbil   = (const float*)d_in[10];
  const float* wproj  = (const float*)d_in[11];
  const float* bproj  = (const float*)d_in[12];
  float* outp = (float*)d_out;

  char* p = (char*)d_ws;
  auto alloc = [&](size_t bytes)->char* {
    char* r = p; p += (bytes + 255) & ~(size_t)255; return r;
  };
  f16*   w16T  = (f16*)  alloc((size_t)R_*F_*F_*2);
  f16*   G16   = (f16*)  alloc((size_t)B_*R_*S_*F_*2);
  f16*   M16   = (f16*)  alloc((size_t)B_*R_*S_*S_*2);
  float* Cpart = (float*)alloc((size_t)12*BS_*F_*4);
  float* h32a  = (float*)alloc((size_t)BS_*F_*4);
  float* h32b  = (float*)alloc((size_t)BS_*F_*4);
  f16*   h16row= (f16*)  alloc((size_t)BS_*F_*2);
  f16*   h16T  = (f16*)  alloc((size_t)BS_*F_*2);
  float* kx    = (float*)alloc((size_t)BS_*F_*4);
  f16*   wkT   = (f16*)  alloc((size_t)F_*F_*2);
  float* vbuf  = (float*)alloc((size_t)R_*F_*4);
  float* ubuf  = (float*)alloc((size_t)B_*R_*S_*4);
  float* dinv  = (float*)alloc((size_t)B_*R_*S_*4);
  float* lgb   = (float*)alloc((size_t)B_*R_*S_*4);
  float* cbuf  = (float*)alloc((size_t)B_*R_*S_*4);
  float* obuf  = (float*)alloc((size_t)B_*F_*4);
  if ((size_t)(p - (char*)d_ws) > ws_size) return;  // workspace insufficient -> fail loudly

  const size_t WL = (size_t)R_*F_*F_;   // w_rgcn layer stride

  // ---- layer 0 (h = x) ----
  kConvWV<<<R_*12, 256, 0, stream>>>(w_rgcn, score_w, w16T, vbuf);
  kTransTo16T<float><<<192, 256, 0, stream>>>(x, h16T);
  kU<<<10496, 256, 0, stream>>>(x, vbuf, ubuf);
  kLogits<<<10496, 256, 0, stream>>>(adj, ubuf, score_b, 0, dinv, lgb);
  kSoftmaxR<<<4, 256, 0, stream>>>(lgb, cbuf);
  kM16<<<5248, 256, 0, stream>>>(adj, cbuf, dinv, M16);
  kGgemm<<<B_*R_*6, 256, 0, stream>>>(M16, h16T, G16);
  kOutGemm<<<576, 256, 0, stream>>>(G16, w16T, Cpart);
  kReduce<<<768, 256, 0, stream>>>(Cpart, h32a, h16row);
  kTransTo16T<f16><<<192, 256, 0, stream>>>(h16row, h16T);

  // ---- layer 1 (h = h32a) ----
  kConvWV<<<R_*12, 256, 0, stream>>>(w_rgcn + WL, score_w + F_, w16T, vbuf);
  kU<<<10496, 256, 0, stream>>>(h32a, vbuf, ubuf);
  kLogits<<<10496, 256, 0, stream>>>(adj, ubuf, score_b, 1, dinv, lgb);
  kSoftmaxR<<<4, 256, 0, stream>>>(lgb, cbuf);
  kM16<<<5248, 256, 0, stream>>>(adj, cbuf, dinv, M16);
  kGgemm<<<B_*R_*6, 256, 0, stream>>>(M16, h16T, G16);
  kOutGemm<<<576, 256, 0, stream>>>(G16, w16T, Cpart);
  kReduce<<<768, 256, 0, stream>>>(Cpart, h32b, h16row);

  // ---- attention ----
  kConvW<<<144, 256, 0, stream>>>(wk, wkT);
  kKx<<<48, 256, 0, stream>>>(h16row, wkT, bk, kx);
  kAttn<<<64, 256, 0, stream>>>(kx, qin, wq, bq, wbil, obuf);
  kProj<<<24, 256, 0, stream>>>(obuf, wproj, bproj, outp);
}

// Round 3
// 514.025 us; speedup vs baseline: 1.1180x; 1.0319x over previous
//
#include <hip/hip_runtime.h>
#include <stdint.h>

#define B_ 8
#define S_ 128
#define R_ 41
#define F_ 768
#define NH_ 8
#define HID_ 96
#define BS_ (B_*S_)
#define SM_SCALE 256.0f
#define NG_ 21   // split-K groups in kOutGemm (20 x 2r + 1 x 1r)

typedef _Float16 f16;
typedef _Float16 f16x8 __attribute__((ext_vector_type(8)));
typedef _Float16 f16x4 __attribute__((ext_vector_type(4)));
typedef float f32x4 __attribute__((ext_vector_type(4)));

#define GLD16(gp, lp) __builtin_amdgcn_global_load_lds((const __attribute__((address_space(1))) uint32_t*)(gp), (__attribute__((address_space(3))) uint32_t*)(lp), 16, 0, 0)

__device__ __forceinline__ float wredsum(float v){
  #pragma unroll
  for (int o=32;o;o>>=1) v += __shfl_down(v,o,64);
  return v;
}

// ---------------- fused: transpose-convert w_rgcn layer -> f16 [r][o][i]  AND  v[r,i]=dot(w[r,i,:],sw) ----------------
__global__ __launch_bounds__(256) void kConvWV(const float* __restrict__ w, const float* __restrict__ sw,
                                               f16* __restrict__ wT, float* __restrict__ v) {
  int bid = blockIdx.x;
  int it = bid % 12, r = bid / 12;
  __shared__ float t[64*68];
  int tid = threadIdx.x;
  int ri = tid >> 2, c = tid & 3;
  float vacc = 0.f;
  for (int ot = 0; ot < 12; ++ot) {
    const float* src = w + ((size_t)r*F_ + (it*64 + ri))*F_ + ot*64 + c*16;
    const float* swp = sw + ot*64 + c*16;
    __syncthreads();   // previous iteration's reads done before overwrite
    #pragma unroll
    for (int j=0;j<4;j++){
      f32x4 v4 = *(const f32x4*)(src + j*4);
      f32x4 s4 = *(const f32x4*)(swp + j*4);
      vacc += v4.x*s4.x + v4.y*s4.y + v4.z*s4.z + v4.w*s4.w;
      *(f32x4*)&t[ri*68 + c*16 + j*4] = v4;
    }
    __syncthreads();
    int ro = tid >> 2;
    f16 outv[16];
    #pragma unroll
    for (int j=0;j<16;j++) outv[j] = (f16)t[(c*16+j)*68 + ro];
    f16* dst = wT + ((size_t)r*F_ + (ot*64+ro))*F_ + it*64 + c*16;
    *(f16x8*)dst = *(f16x8*)&outv[0];
    *(f16x8*)(dst+8) = *(f16x8*)&outv[8];
  }
  vacc += __shfl_down(vacc, 1, 64);
  vacc += __shfl_down(vacc, 2, 64);
  if (c == 0) v[(size_t)r*F_ + it*64 + ri] = vacc;
}

// ---------------- transpose-convert fp32 [768][768] -> f16 [o][i] (for wk) ----------------
__global__ __launch_bounds__(256) void kConvW(const float* __restrict__ w, f16* __restrict__ wT) {
  int bid = blockIdx.x;
  int ot = bid % 12; int it = (bid/12) % 12; int r = bid / 144;
  __shared__ float t[64*68];
  int tid = threadIdx.x;
  int ri = tid >> 2, c = tid & 3;
  const float* src = w + ((size_t)r*F_ + (it*64 + ri))*F_ + ot*64 + c*16;
  #pragma unroll
  for (int j=0;j<4;j++){
    f32x4 v4 = *(const f32x4*)(src + j*4);
    *(f32x4*)&t[ri*68 + c*16 + j*4] = v4;
  }
  __syncthreads();
  int ro = tid >> 2;
  f16 outv[16];
  #pragma unroll
  for (int j=0;j<16;j++) outv[j] = (f16)t[(c*16+j)*68 + ro];
  f16* dst = wT + ((size_t)r*F_ + (ot*64+ro))*F_ + it*64 + c*16;
  *(f16x8*)dst = *(f16x8*)&outv[0];
  *(f16x8*)(dst+8) = *(f16x8*)&outv[8];
}

// ---------------- transpose [b][s][f] (T=float or f16) -> f16 [b][f][s] ----------------
template<typename T>
__global__ __launch_bounds__(256) void kTransTo16T(const T* __restrict__ h, f16* __restrict__ hT) {
  int bid = blockIdx.x;
  int st = bid & 1; int ft = (bid>>1) % 12; int b = bid / 24;
  __shared__ f16 t[64*72];
  int tid = threadIdx.x;
  int sl = tid>>2, c = tid&3;
  const T* src = h + ((size_t)b*S_ + st*64 + sl)*F_ + ft*64 + c*16;
  f16 tmp[16];
  #pragma unroll
  for (int j=0;j<16;j++) tmp[j] = (f16)src[j];
  *(f16x8*)&t[sl*72 + c*16]     = *(f16x8*)&tmp[0];
  *(f16x8*)&t[sl*72 + c*16 + 8] = *(f16x8*)&tmp[8];
  __syncthreads();
  int fl = tid>>2;
  f16 outv[16];
  #pragma unroll
  for (int j=0;j<16;j++) outv[j] = t[(c*16+j)*72 + fl];
  f16* dst = hT + ((size_t)b*F_ + ft*64 + fl)*S_ + st*64 + c*16;
  *(f16x8*)dst = *(f16x8*)&outv[0];
  *(f16x8*)(dst+8) = *(f16x8*)&outv[8];
}

// ---------------- u[(b*R+r)*S+k] = dot(h[b,k,:], v[r,:]) ----------------
__global__ __launch_bounds__(256) void kU(const float* __restrict__ h, const float* __restrict__ v, float* __restrict__ u) {
  int idx = blockIdx.x*4 + (threadIdx.x>>6);
  int lane = threadIdx.x&63;
  int k = idx & 127;
  int br = idx >> 7;
  int r = br % R_;
  int b = br / R_;
  const float* hr = h + ((size_t)b*S_ + k)*F_ + lane*12;
  const float* vr = v + (size_t)r*F_ + lane*12;
  float acc=0.f;
  #pragma unroll
  for (int j=0;j<3;j++){
    f32x4 a = *(const f32x4*)(hr+j*4);
    f32x4 c4 = *(const f32x4*)(vr+j*4);
    acc += a.x*c4.x+a.y*c4.y+a.z*c4.z+a.w*c4.w;
  }
  acc = wredsum(acc);
  if (lane==0) u[idx] = acc;
}

// ---------------- denom + logits per (b,r,s) ----------------
__global__ __launch_bounds__(256) void kLogits(const float* __restrict__ adj, const float* __restrict__ u,
                        const float* __restrict__ sb_all, int l,
                        float* __restrict__ dinv, float* __restrict__ lg) {
  int idx = blockIdx.x*4 + (threadIdx.x>>6);   // (b*R+r)*S + s
  int lane = threadIdx.x&63;
  const float* arow = adj + (size_t)idx*S_;
  int br = idx >> 7;
  const float* up = u + (size_t)br*S_;
  float a0 = arow[lane], a1 = arow[lane+64];
  float u0 = up[lane],   u1 = up[lane+64];
  float ssum = a0+a1;
  float sdot = a0*u0 + a1*u1;
  ssum = wredsum(ssum);
  sdot = wredsum(sdot);
  if (lane==0){
    float dv = (ssum==0.0f) ? 1.0f : (1.0f/ssum);
    dinv[idx] = dv;
    lg[idx] = sdot*dv + sb_all[l];
  }
}

// ---------------- softmax over r (41) per (b,s) ----------------
__global__ __launch_bounds__(256) void kSoftmaxR(const float* __restrict__ lg, float* __restrict__ c) {
  int t = blockIdx.x*256 + threadIdx.x;  // 0..1023
  int b = t >> 7, s = t & 127;
  float vals[R_];
  float mx = -1e30f;
  #pragma unroll
  for (int r=0;r<R_;r++){ float x = lg[((size_t)b*R_+r)*S_ + s]; vals[r]=x; mx = fmaxf(mx,x); }
  float sum=0.f;
  #pragma unroll
  for (int r=0;r<R_;r++){ vals[r] = expf(vals[r]-mx); sum += vals[r]; }
  float inv = 1.0f/sum;
  #pragma unroll
  for (int r=0;r<R_;r++) c[((size_t)b*R_+r)*S_+s] = vals[r]*inv;
}

// ---------------- M16 = f16(SM * c * dinv * adj) ----------------
__global__ __launch_bounds__(256) void kM16(const float* __restrict__ adj, const float* __restrict__ c,
                     const float* __restrict__ dinv, f16* __restrict__ M) {
  int t = blockIdx.x*256 + threadIdx.x;
  int brs = t >> 5; int k4 = (t & 31) * 4;
  float a = SM_SCALE * c[brs] * dinv[brs];
  f32x4 v4 = *(const f32x4*)(adj + (size_t)brs*S_ + k4);
  f16x4 o;
  o[0]=(f16)(v4.x*a); o[1]=(f16)(v4.y*a); o[2]=(f16)(v4.z*a); o[3]=(f16)(v4.w*a);
  *(f16x4*)(M + (size_t)brs*S_ + k4) = o;
}

// ---------------- G[b,r] = M16[b,r] (128x128) @ h16T^T -> 128x128 col tile ----------------
__global__ __launch_bounds__(256) void kGgemm(const f16* __restrict__ M, const f16* __restrict__ hT, f16* __restrict__ G) {
  __shared__ f16 lds[2*16384];   // 64 KB
  f16* lsA = lds;              // [128 s][128 k]
  f16* lsB = lds + 16384;      // [128 i][128 k]
  int bid = blockIdx.x;
  int nt = bid % 6; int r = (bid/6) % R_; int b = bid/(6*R_);
  int tid = threadIdx.x, wid = tid>>6, lane = tid&63;
  const f16* Ab = M + (size_t)(b*R_ + r)*(S_*S_);
  const f16* Bb = hT + ((size_t)b*F_ + nt*128)*S_;
  #pragma unroll
  for (int j=0;j<8;j++){
    int qd = wid*8 + j;
    GLD16(Ab + qd*512 + lane*8, lsA + qd*512);
    GLD16(Bb + qd*512 + lane*8, lsB + qd*512);
  }
  __syncthreads();
  f32x4 acc[4][4] = {};
  int wr = wid>>1, wc = wid&1;
  int lr = lane&15, kk0 = (lane>>4)*8;
  #pragma unroll
  for (int ks=0;ks<4;ks++){
    int kk = ks*32 + kk0;
    f16x8 av[4], bv[4];
    #pragma unroll
    for (int i=0;i<4;i++) av[i] = *(const f16x8*)&lsA[(wr*64+i*16+lr)*128 + kk];
    #pragma unroll
    for (int i=0;i<4;i++) bv[i] = *(const f16x8*)&lsB[(wc*64+i*16+lr)*128 + kk];
    #pragma unroll
    for (int mi=0;mi<4;mi++)
      #pragma unroll
      for (int ni=0;ni<4;ni++)
        acc[mi][ni] = __builtin_amdgcn_mfma_f32_16x16x32_f16(av[mi],bv[ni],acc[mi][ni],0,0,0);
  }
  __syncthreads();
  // repack through LDS [128][136] then coalesced store of 128-col tile
  #pragma unroll
  for (int mi=0;mi<4;mi++)
    #pragma unroll
    for (int ni=0;ni<4;ni++){
      int row = wr*64 + mi*16 + (lane>>4)*4;
      int col = wc*64 + ni*16 + lr;
      #pragma unroll
      for (int i=0;i<4;i++)
        lds[(row+i)*136 + col] = (f16)acc[mi][ni][i];
    }
  __syncthreads();
  int row = tid>>1, seg = tid&1;
  f16* dst = G + ((size_t)(b*R_ + r)*S_ + row)*F_ + nt*128 + seg*64;
  const f16* sl = lds + row*136 + seg*64;
  #pragma unroll
  for (int j=0;j<8;j++) *(f16x8*)(dst + j*8) = *(const f16x8*)(sl + j*8);
}

// ---------------- big GEMM: Cpart[g] = A''(1024 x K_g) @ W'(K_g x 768), 256x256 tiles, split-K over r ----------------
__global__ __launch_bounds__(512,2) void kOutGemm(const f16* __restrict__ G, const f16* __restrict__ WT, float* __restrict__ Cp) {
  __shared__ f16 lsA[256*64];   // [256 rows (b,s)][64 k]
  __shared__ f16 lsB[256*64];   // [256 rows (o)  ][64 k]
  int bid = blockIdx.x;
  int t12 = bid % 12, g = bid / 12;
  int nt = t12 % 3, mt = t12 / 3;
  int r0 = (g<20)? 2*g : 40;
  int nr = (g<20)? 2 : 1;
  int tid = threadIdx.x, wid = tid>>6, lane = tid&63;
  size_t abase[4], bbase[4];
  #pragma unroll
  for (int j=0;j<4;j++){
    int chunk = wid*4 + j;                 // 0..31, each = 8 rows x 64 k
    int arow = mt*256 + chunk*8 + (lane>>3);
    int b = arow >> 7, s = arow & 127;
    abase[j] = ((size_t)b*R_*S_ + s)*(size_t)F_ + (lane&7)*8;  // + r*S_*F_ + it*64
    int orow = nt*256 + chunk*8 + (lane>>3);
    bbase[j] = (size_t)orow*F_ + (lane&7)*8;                   // + r*F_*F_ + it*64
  }
  f32x4 acc[8][4] = {};
  int wr = wid>>2, wc = wid&3;             // 2 (M) x 4 (N) waves, each 128x64 out
  int lr = lane&15, kk0 = (lane>>4)*8;
  for (int rr=0; rr<nr; ++rr){
    int r = r0 + rr;
    const f16* Ar = G  + (size_t)r*S_*F_;
    const f16* Br = WT + (size_t)r*F_*F_;
    for (int it=0; it<12; ++it){
      #pragma unroll
      for (int j=0;j<4;j++){
        int chunk = wid*4 + j;
        GLD16(Ar + abase[j] + it*64, lsA + chunk*512);
        GLD16(Br + bbase[j] + it*64, lsB + chunk*512);
      }
      __syncthreads();
      #pragma unroll
      for (int ks=0;ks<2;ks++){
        int kk = ks*32 + kk0;
        f16x8 av[8], bv[4];
        #pragma unroll
        for (int i=0;i<8;i++) av[i] = *(const f16x8*)&lsA[(wr*128+i*16+lr)*64 + kk];
        #pragma unroll
        for (int i=0;i<4;i++) bv[i] = *(const f16x8*)&lsB[(wc*64+i*16+lr)*64 + kk];
        #pragma unroll
        for (int mi=0;mi<8;mi++)
          #pragma unroll
          for (int ni=0;ni<4;ni++)
            acc[mi][ni] = __builtin_amdgcn_mfma_f32_16x16x32_f16(av[mi],bv[ni],acc[mi][ni],0,0,0);
      }
      __syncthreads();
    }
  }
  #pragma unroll
  for (int mi=0;mi<8;mi++)
    #pragma unroll
    for (int ni=0;ni<4;ni++){
      int row = mt*256 + wr*128 + mi*16 + (lane>>4)*4;
      int col = nt*256 + wc*64 + ni*16 + lr;
      #pragma unroll
      for (int i=0;i<4;i++)
        Cp[((size_t)g*BS_ + row + i)*F_ + col] = acc[mi][ni][i];
    }
}

// ---------------- reduce split-K partials, /SM, relu, write h32 + h16 ----------------
__global__ __launch_bounds__(256) void kReduce(const float* __restrict__ Cp, float* __restrict__ h32, f16* __restrict__ h16o) {
  int t = blockIdx.x*256 + threadIdx.x;
  size_t i4 = (size_t)t*4;
  f32x4 s = {};
  #pragma unroll
  for (int g=0; g<NG_; g++){
    f32x4 v4 = *(const f32x4*)(Cp + (size_t)g*BS_*F_ + i4);
    s.x += v4.x; s.y += v4.y; s.z += v4.z; s.w += v4.w;
  }
  const float inv = 1.0f/SM_SCALE;
  f32x4 rr;
  rr.x = fmaxf(s.x*inv, 0.f); rr.y = fmaxf(s.y*inv, 0.f);
  rr.z = fmaxf(s.z*inv, 0.f); rr.w = fmaxf(s.w*inv, 0.f);
  *(f32x4*)(h32 + i4) = rr;
  f16x4 o; o[0]=(f16)rr.x; o[1]=(f16)rr.y; o[2]=(f16)rr.z; o[3]=(f16)rr.w;
  *(f16x4*)(h16o + i4) = o;
}

// ---------------- kx = h2 @ wk + bk  (1024x768x768, MFMA) ----------------
__global__ __launch_bounds__(256) void kKx(const f16* __restrict__ A, const f16* __restrict__ BT,
                    const float* __restrict__ bias, float* __restrict__ C) {
  __shared__ f16 lsA[128*64];
  __shared__ f16 lsB[128*64];
  int bid = blockIdx.x;
  int nt = bid % 6, mt = bid / 6;
  int tid = threadIdx.x, wid = tid>>6, lane = tid&63;
  size_t abase[4], bbase[4];
  #pragma unroll
  for (int j=0;j<4;j++){
    int qd = wid*4 + j;
    int row = mt*128 + qd*8 + (lane>>3);
    abase[j] = (size_t)row*F_ + (lane&7)*8;
    int o = nt*128 + qd*8 + (lane>>3);
    bbase[j] = (size_t)o*F_ + (lane&7)*8;
  }
  f32x4 acc[4][4] = {};
  int wr = wid>>1, wc = wid&1;
  int lr = lane&15, kk0 = (lane>>4)*8;
  for (int it=0; it<12; ++it){
    #pragma unroll
    for (int j=0;j<4;j++){
      int qd = wid*4+j;
      GLD16(A + abase[j] + it*64, lsA + qd*512);
      GLD16(BT + bbase[j] + it*64, lsB + qd*512);
    }
    __syncthreads();
    #pragma unroll
    for (int ks=0;ks<2;ks++){
      int kk = ks*32 + kk0;
      f16x8 av[4], bv[4];
      #pragma unroll
      for (int i=0;i<4;i++) av[i] = *(const f16x8*)&lsA[(wr*64+i*16+lr)*64 + kk];
      #pragma unroll
      for (int i=0;i<4;i++) bv[i] = *(const f16x8*)&lsB[(wc*64+i*16+lr)*64 + kk];
      #pragma unroll
      for (int mi=0;mi<4;mi++)
        #pragma unroll
        for (int ni=0;ni<4;ni++)
          acc[mi][ni] = __builtin_amdgcn_mfma_f32_16x16x32_f16(av[mi],bv[ni],acc[mi][ni],0,0,0);
    }
    __syncthreads();
  }
  #pragma unroll
  for (int mi=0;mi<4;mi++)
    #pragma unroll
    for (int ni=0;ni<4;ni++){
      int row = mt*128 + wr*64 + mi*16 + (lane>>4)*4;
      int col = nt*128 + wc*64 + ni*16 + lr;
      float bb = bias[col];
      #pragma unroll
      for (int i=0;i<4;i++)
        C[(size_t)(row+i)*F_ + col] = acc[mi][ni][i] + bb;
    }
}

// ---------------- attention core per (b,h): qx, qw, score, softmax, o ----------------
__global__ __launch_bounds__(256) void kAttn(const float* __restrict__ kx, const float* __restrict__ qin,
                      const float* __restrict__ wq, const float* __restrict__ bq,
                      const float* __restrict__ wbil, float* __restrict__ obuf) {
  int bid = blockIdx.x; int h = bid & 7; int b = bid >> 3;
  __shared__ float qx[HID_], qw[HID_], sc[S_];
  __shared__ float smax, ssum;
  int t = threadIdx.x;
  if (t < HID_) {
    float a0=0.f,a1=0.f,a2=0.f,a3=0.f;
    const float* qp = qin + (size_t)b*F_;
    const float* wp = wq + h*HID_ + t;
    for (int i=0;i<F_;i+=4){
      a0 += qp[i]*wp[(size_t)i*F_];
      a1 += qp[i+1]*wp[(size_t)(i+1)*F_];
      a2 += qp[i+2]*wp[(size_t)(i+2)*F_];
      a3 += qp[i+3]*wp[(size_t)(i+3)*F_];
    }
    qx[t] = a0+a1+a2+a3 + bq[h*HID_+t];
  }
  __syncthreads();
  if (t < HID_) {
    float a0=0.f,a1=0.f;
    for (int e=0;e<HID_;e+=2){ a0 += qx[e]*wbil[e*HID_+t]; a1 += qx[e+1]*wbil[(e+1)*HID_+t]; }
    qw[t] = a0+a1;
  }
  __syncthreads();
  if (t < S_) {
    float a0=0.f,a1=0.f;
    const float* kp = kx + ((size_t)b*S_ + t)*F_ + h*HID_;
    for (int e=0;e<HID_;e+=2){ a0 += qw[e]*kp[e]; a1 += qw[e+1]*kp[e+1]; }
    sc[t] = a0+a1;
  }
  __syncthreads();
  if (t < 64) {
    float m = fmaxf(sc[t], sc[t+64]);
    #pragma unroll
    for (int o=32;o;o>>=1) m = fmaxf(m, __shfl_down(m,o,64));
    if (t==0) smax = m;
  }
  __syncthreads();
  if (t < S_) sc[t] = expf(sc[t]-smax);
  __syncthreads();
  if (t < 64) {
    float s = sc[t] + sc[t+64];
    s = wredsum(s);
    if (t==0) ssum = s;
  }
  __syncthreads();
  if (t < HID_) {
    float a0=0.f,a1=0.f;
    const float* kp = kx + ((size_t)b*S_)*F_ + h*HID_ + t;
    for (int k=0;k<S_;k+=2){ a0 += sc[k]*kp[(size_t)k*F_]; a1 += sc[k+1]*kp[(size_t)(k+1)*F_]; }
    obuf[(size_t)b*F_ + h*HID_ + t] = (a0+a1)/ssum;
  }
}

// ---------------- final projection out = o @ wproj + bproj ----------------
__global__ __launch_bounds__(256) void kProj(const float* __restrict__ obuf, const float* __restrict__ wproj,
                      const float* __restrict__ bproj, float* __restrict__ outp) {
  int bid = blockIdx.x; int b = bid/3, seg = bid%3;
  int t = threadIdx.x;
  __shared__ float ov[F_];
  for (int j=t;j<F_;j+=256) ov[j] = obuf[(size_t)b*F_ + j];
  __syncthreads();
  int col = seg*256 + t;
  float a0=0.f,a1=0.f,a2=0.f,a3=0.f;
  for (int j=0;j<F_;j+=4){
    a0 += ov[j]*wproj[(size_t)j*F_+col];
    a1 += ov[j+1]*wproj[(size_t)(j+1)*F_+col];
    a2 += ov[j+2]*wproj[(size_t)(j+2)*F_+col];
    a3 += ov[j+3]*wproj[(size_t)(j+3)*F_+col];
  }
  outp[(size_t)b*F_ + col] = bproj[col] + a0+a1+a2+a3;
}

extern "C" void kernel_launch(void* const* d_in, const int* in_sizes, int n_in,
                              void* d_out, int out_size, void* d_ws, size_t ws_size,
                              hipStream_t stream) {
  (void)in_sizes; (void)n_in; (void)out_size;
  const float* x      = (const float*)d_in[0];
  const float* adj    = (const float*)d_in[1];
  const float* qin    = (const float*)d_in[2];
  const float* w_rgcn = (const float*)d_in[3];
  const float* score_w= (const float*)d_in[4];
  const float* score_b= (const float*)d_in[5];
  const float* wk     = (const float*)d_in[6];
  const float* bk     = (const float*)d_in[7];
  const float* wq     = (const float*)d_in[8];
  const float* bq     = (const float*)d_in[9];
  const float* wbil   = (const float*)d_in[10];
  const float* wproj  = (const float*)d_in[11];
  const float* bproj  = (const float*)d_in[12];
  float* outp = (float*)d_out;

  char* p = (char*)d_ws;
  auto alloc = [&](size_t bytes)->char* {
    char* r = p; p += (bytes + 255) & ~(size_t)255; return r;
  };
  f16*   w16T  = (f16*)  alloc((size_t)R_*F_*F_*2);
  f16*   G16   = (f16*)  alloc((size_t)B_*R_*S_*F_*2);
  f16*   M16   = (f16*)  alloc((size_t)B_*R_*S_*S_*2);
  float* Cpart = (float*)alloc((size_t)NG_*BS_*F_*4);
  float* h32a  = (float*)alloc((size_t)BS_*F_*4);
  float* h32b  = (float*)alloc((size_t)BS_*F_*4);
  f16*   h16row= (f16*)  alloc((size_t)BS_*F_*2);
  f16*   h16T  = (f16*)  alloc((size_t)BS_*F_*2);
  float* kx    = (float*)alloc((size_t)BS_*F_*4);
  f16*   wkT   = (f16*)  alloc((size_t)F_*F_*2);
  float* vbuf  = (float*)alloc((size_t)R_*F_*4);
  float* ubuf  = (float*)alloc((size_t)B_*R_*S_*4);
  float* dinv  = (float*)alloc((size_t)B_*R_*S_*4);
  float* lgb   = (float*)alloc((size_t)B_*R_*S_*4);
  float* cbuf  = (float*)alloc((size_t)B_*R_*S_*4);
  float* obuf  = (float*)alloc((size_t)B_*F_*4);
  if ((size_t)(p - (char*)d_ws) > ws_size) return;  // workspace insufficient -> fail loudly

  const size_t WL = (size_t)R_*F_*F_;   // w_rgcn layer stride

  // ---- layer 0 (h = x) ----
  kConvWV<<<R_*12, 256, 0, stream>>>(w_rgcn, score_w, w16T, vbuf);
  kTransTo16T<float><<<192, 256, 0, stream>>>(x, h16T);
  kU<<<10496, 256, 0, stream>>>(x, vbuf, ubuf);
  kLogits<<<10496, 256, 0, stream>>>(adj, ubuf, score_b, 0, dinv, lgb);
  kSoftmaxR<<<4, 256, 0, stream>>>(lgb, cbuf);
  kM16<<<5248, 256, 0, stream>>>(adj, cbuf, dinv, M16);
  kGgemm<<<B_*R_*6, 256, 0, stream>>>(M16, h16T, G16);
  kOutGemm<<<12*NG_, 512, 0, stream>>>(G16, w16T, Cpart);
  kReduce<<<768, 256, 0, stream>>>(Cpart, h32a, h16row);
  kTransTo16T<f16><<<192, 256, 0, stream>>>(h16row, h16T);

  // ---- layer 1 (h = h32a) ----
  kConvWV<<<R_*12, 256, 0, stream>>>(w_rgcn + WL, score_w + F_, w16T, vbuf);
  kU<<<10496, 256, 0, stream>>>(h32a, vbuf, ubuf);
  kLogits<<<10496, 256, 0, stream>>>(adj, ubuf, score_b, 1, dinv, lgb);
  kSoftmaxR<<<4, 256, 0, stream>>>(lgb, cbuf);
  kM16<<<5248, 256, 0, stream>>>(adj, cbuf, dinv, M16);
  kGgemm<<<B_*R_*6, 256, 0, stream>>>(M16, h16T, G16);
  kOutGemm<<<12*NG_, 512, 0, stream>>>(G16, w16T, Cpart);
  kReduce<<<768, 256, 0, stream>>>(Cpart, h32b, h16row);

  // ---- attention ----
  kConvW<<<144, 256, 0, stream>>>(wk, wkT);
  kKx<<<48, 256, 0, stream>>>(h16row, wkT, bk, kx);
  kAttn<<<64, 256, 0, stream>>>(kx, qin, wq, bq, wbil, obuf);
  kProj<<<24, 256, 0, stream>>>(obuf, wproj, bproj, outp);
}

// Round 4
// 483.581 us; speedup vs baseline: 1.1884x; 1.0630x over previous
//
#include <hip/hip_runtime.h>
#include <stdint.h>

#define B_ 8
#define S_ 128
#define R_ 41
#define F_ 768
#define NH_ 8
#define HID_ 96
#define BS_ (B_*S_)
#define SM_SCALE 256.0f
#define NG_ 21   // split-K groups in kOutGemm (20 x 2r + 1 x 1r)

typedef _Float16 f16;
typedef _Float16 f16x8 __attribute__((ext_vector_type(8)));
typedef _Float16 f16x4 __attribute__((ext_vector_type(4)));
typedef _Float16 f16x2 __attribute__((ext_vector_type(2)));
typedef float f32x4 __attribute__((ext_vector_type(4)));
typedef float f32x2 __attribute__((ext_vector_type(2)));

#define GLD16(gp, lp) __builtin_amdgcn_global_load_lds((const __attribute__((address_space(1))) uint32_t*)(gp), (__attribute__((address_space(3))) uint32_t*)(lp), 16, 0, 0)

__device__ __forceinline__ float wredsum(float v){
  #pragma unroll
  for (int o=32;o;o>>=1) v += __shfl_down(v,o,64);
  return v;
}

// ---------------- fused: transpose-convert w_rgcn layer -> f16 [r][o][i]  AND  v[r,i]=dot(w[r,i,:],sw) ----------------
__global__ __launch_bounds__(256) void kConvWV(const float* __restrict__ w, const float* __restrict__ sw,
                                               f16* __restrict__ wT, float* __restrict__ v) {
  int bid = blockIdx.x;
  int it = bid % 12, r = bid / 12;
  __shared__ float t[64*68];
  int tid = threadIdx.x;
  int ri = tid >> 2, c = tid & 3;
  float vacc = 0.f;
  for (int ot = 0; ot < 12; ++ot) {
    const float* src = w + ((size_t)r*F_ + (it*64 + ri))*F_ + ot*64 + c*16;
    const float* swp = sw + ot*64 + c*16;
    __syncthreads();   // previous iteration's reads done before overwrite
    #pragma unroll
    for (int j=0;j<4;j++){
      f32x4 v4 = *(const f32x4*)(src + j*4);
      f32x4 s4 = *(const f32x4*)(swp + j*4);
      vacc += v4.x*s4.x + v4.y*s4.y + v4.z*s4.z + v4.w*s4.w;
      *(f32x4*)&t[ri*68 + c*16 + j*4] = v4;
    }
    __syncthreads();
    int ro = tid >> 2;
    f16 outv[16];
    #pragma unroll
    for (int j=0;j<16;j++) outv[j] = (f16)t[(c*16+j)*68 + ro];
    f16* dst = wT + ((size_t)r*F_ + (ot*64+ro))*F_ + it*64 + c*16;
    *(f16x8*)dst = *(f16x8*)&outv[0];
    *(f16x8*)(dst+8) = *(f16x8*)&outv[8];
  }
  vacc += __shfl_down(vacc, 1, 64);
  vacc += __shfl_down(vacc, 2, 64);
  if (c == 0) v[(size_t)r*F_ + it*64 + ri] = vacc;
}

// ---------------- transpose-convert fp32 [768][768] -> f16 [o][i] (for wk) ----------------
__global__ __launch_bounds__(256) void kConvW(const float* __restrict__ w, f16* __restrict__ wT) {
  int bid = blockIdx.x;
  int ot = bid % 12; int it = (bid/12) % 12; int r = bid / 144;
  __shared__ float t[64*68];
  int tid = threadIdx.x;
  int ri = tid >> 2, c = tid & 3;
  const float* src = w + ((size_t)r*F_ + (it*64 + ri))*F_ + ot*64 + c*16;
  #pragma unroll
  for (int j=0;j<4;j++){
    f32x4 v4 = *(const f32x4*)(src + j*4);
    *(f32x4*)&t[ri*68 + c*16 + j*4] = v4;
  }
  __syncthreads();
  int ro = tid >> 2;
  f16 outv[16];
  #pragma unroll
  for (int j=0;j<16;j++) outv[j] = (f16)t[(c*16+j)*68 + ro];
  f16* dst = wT + ((size_t)r*F_ + (ot*64+ro))*F_ + it*64 + c*16;
  *(f16x8*)dst = *(f16x8*)&outv[0];
  *(f16x8*)(dst+8) = *(f16x8*)&outv[8];
}

// ---------------- transpose [b][s][f] (T=float or f16) -> f16 [b][f][s] ----------------
template<typename T>
__global__ __launch_bounds__(256) void kTransTo16T(const T* __restrict__ h, f16* __restrict__ hT) {
  int bid = blockIdx.x;
  int st = bid & 1; int ft = (bid>>1) % 12; int b = bid / 24;
  __shared__ f16 t[64*72];
  int tid = threadIdx.x;
  int sl = tid>>2, c = tid&3;
  const T* src = h + ((size_t)b*S_ + st*64 + sl)*F_ + ft*64 + c*16;
  f16 tmp[16];
  #pragma unroll
  for (int j=0;j<16;j++) tmp[j] = (f16)src[j];
  *(f16x8*)&t[sl*72 + c*16]     = *(f16x8*)&tmp[0];
  *(f16x8*)&t[sl*72 + c*16 + 8] = *(f16x8*)&tmp[8];
  __syncthreads();
  int fl = tid>>2;
  f16 outv[16];
  #pragma unroll
  for (int j=0;j<16;j++) outv[j] = t[(c*16+j)*72 + fl];
  f16* dst = hT + ((size_t)b*F_ + ft*64 + fl)*S_ + st*64 + c*16;
  *(f16x8*)dst = *(f16x8*)&outv[0];
  *(f16x8*)(dst+8) = *(f16x8*)&outv[8];
}

// ---------------- fused kU+kLogits: per (b,r): u-row in LDS, then denom+logits ----------------
__global__ __launch_bounds__(256) void kUL(const float* __restrict__ h, const float* __restrict__ v,
                    const float* __restrict__ adj, const float* __restrict__ sb_all, int l,
                    float* __restrict__ dinv, float* __restrict__ lg) {
  int bid = blockIdx.x;           // b*R + r
  int r = bid % R_, b = bid / R_;
  __shared__ float v_s[F_];
  __shared__ float u_s[S_];
  int tid = threadIdx.x;
  #pragma unroll
  for (int j=0;j<3;j++) v_s[tid + j*256] = v[(size_t)r*F_ + tid + j*256];
  __syncthreads();
  int wid = tid>>6, lane = tid&63;
  // u phase: wave wid handles k = wid*32 .. wid*32+31
  for (int kl=0; kl<32; ++kl){
    int k = wid*32 + kl;
    const float* hr = h + ((size_t)b*S_ + k)*F_ + lane*12;
    const float* vp = &v_s[lane*12];
    float acc=0.f;
    #pragma unroll
    for (int j=0;j<3;j++){
      f32x4 a = *(const f32x4*)(hr+j*4);
      f32x4 c4 = *(const f32x4*)(vp+j*4);
      acc += a.x*c4.x+a.y*c4.y+a.z*c4.z+a.w*c4.w;
    }
    acc = wredsum(acc);
    if (lane==0) u_s[k] = acc;
  }
  __syncthreads();
  // logits phase: thread t: s = t>>1, half = t&1 (adjacent lanes combine)
  int s = tid>>1, half = tid&1;
  const float* arow = adj + ((size_t)bid*S_ + s)*S_ + half*64;
  const float* up = &u_s[half*64];
  float ssum=0.f, sdot=0.f;
  #pragma unroll
  for (int j=0;j<16;j++){
    f32x4 a = *(const f32x4*)(arow + j*4);
    ssum += a.x+a.y+a.z+a.w;
    sdot += a.x*up[j*4] + a.y*up[j*4+1] + a.z*up[j*4+2] + a.w*up[j*4+3];
  }
  ssum += __shfl_xor(ssum,1,64);
  sdot += __shfl_xor(sdot,1,64);
  if (half==0){
    float dv = (ssum==0.0f)?1.0f:(1.0f/ssum);
    dinv[(size_t)bid*S_ + s] = dv;
    lg[(size_t)bid*S_ + s] = sdot*dv + sb_all[l];
  }
}

// ---------------- fused kSoftmaxR+kM16: per (b,s): softmax over r, write M16 rows ----------------
__global__ __launch_bounds__(64) void kSM16(const float* __restrict__ lg, const float* __restrict__ dinv,
                     const float* __restrict__ adj, f16* __restrict__ M) {
  int bid = blockIdx.x;          // b*S + s
  int b = bid >> 7, s = bid & 127;
  int lane = threadIdx.x;
  __shared__ float coef[R_];
  float x = (lane < R_) ? lg[((size_t)b*R_ + lane)*S_ + s] : -1e30f;
  float m = x;
  #pragma unroll
  for (int o=32;o;o>>=1) m = fmaxf(m, __shfl_xor(m,o,64));
  float e = (lane < R_) ? expf(x - m) : 0.f;
  float sum = e;
  #pragma unroll
  for (int o=32;o;o>>=1) sum += __shfl_xor(sum,o,64);
  if (lane < R_) coef[lane] = e/sum * SM_SCALE * dinv[((size_t)b*R_ + lane)*S_ + s];
  __syncthreads();
  for (int r=0;r<R_;r++){
    float cc = coef[r];
    size_t base = (((size_t)(b*R_+r))*S_ + s)*S_ + lane*2;
    f32x2 a2 = *(const f32x2*)(adj + base);
    f16x2 o2; o2[0]=(f16)(a2.x*cc); o2[1]=(f16)(a2.y*cc);
    *(f16x2*)(M + base) = o2;
  }
}

// ---------------- G[b,r] = M16[b,r] (128x128) @ h16T^T -> 128x128 col tile ----------------
__global__ __launch_bounds__(256) void kGgemm(const f16* __restrict__ M, const f16* __restrict__ hT, f16* __restrict__ G) {
  __shared__ f16 lds[2*16384];   // 64 KB
  f16* lsA = lds;              // [128 s][128 k]
  f16* lsB = lds + 16384;      // [128 i][128 k]
  int bid = blockIdx.x;
  int nt = bid % 6; int r = (bid/6) % R_; int b = bid/(6*R_);
  int tid = threadIdx.x, wid = tid>>6, lane = tid&63;
  const f16* Ab = M + (size_t)(b*R_ + r)*(S_*S_);
  const f16* Bb = hT + ((size_t)b*F_ + nt*128)*S_;
  #pragma unroll
  for (int j=0;j<8;j++){
    int qd = wid*8 + j;
    GLD16(Ab + qd*512 + lane*8, lsA + qd*512);
    GLD16(Bb + qd*512 + lane*8, lsB + qd*512);
  }
  __syncthreads();
  f32x4 acc[4][4] = {};
  int wr = wid>>1, wc = wid&1;
  int lr = lane&15, kk0 = (lane>>4)*8;
  #pragma unroll
  for (int ks=0;ks<4;ks++){
    int kk = ks*32 + kk0;
    f16x8 av[4], bv[4];
    #pragma unroll
    for (int i=0;i<4;i++) av[i] = *(const f16x8*)&lsA[(wr*64+i*16+lr)*128 + kk];
    #pragma unroll
    for (int i=0;i<4;i++) bv[i] = *(const f16x8*)&lsB[(wc*64+i*16+lr)*128 + kk];
    #pragma unroll
    for (int mi=0;mi<4;mi++)
      #pragma unroll
      for (int ni=0;ni<4;ni++)
        acc[mi][ni] = __builtin_amdgcn_mfma_f32_16x16x32_f16(av[mi],bv[ni],acc[mi][ni],0,0,0);
  }
  __syncthreads();
  #pragma unroll
  for (int mi=0;mi<4;mi++)
    #pragma unroll
    for (int ni=0;ni<4;ni++){
      int row = wr*64 + mi*16 + (lane>>4)*4;
      int col = wc*64 + ni*16 + lr;
      #pragma unroll
      for (int i=0;i<4;i++)
        lds[(row+i)*136 + col] = (f16)acc[mi][ni][i];
    }
  __syncthreads();
  int row = tid>>1, seg = tid&1;
  f16* dst = G + ((size_t)(b*R_ + r)*S_ + row)*F_ + nt*128 + seg*64;
  const f16* sl = lds + row*136 + seg*64;
  #pragma unroll
  for (int j=0;j<8;j++) *(f16x8*)(dst + j*8) = *(const f16x8*)(sl + j*8);
}

// ---------------- big GEMM: 256x256 tiles, split-K over r, 2-phase prefetch double-buffer ----------------
__global__ __launch_bounds__(512,2) void kOutGemm(const f16* __restrict__ G, const f16* __restrict__ WT, float* __restrict__ Cp) {
  __shared__ f16 ls[2][2][256*64];   // [buf][A/B] = 128 KB total
  int bid = blockIdx.x;
  int t12 = bid % 12, g = bid / 12;
  int nt = t12 % 3, mt = t12 / 3;
  int r0 = (g<20)? 2*g : 40;
  int nr = (g<20)? 2 : 1;
  int tid = threadIdx.x, wid = tid>>6, lane = tid&63;
  size_t abase[4], bbase[4];
  #pragma unroll
  for (int j=0;j<4;j++){
    int chunk = wid*4 + j;                 // 0..31, each = 8 rows x 64 k
    int arow = mt*256 + chunk*8 + (lane>>3);
    int b = arow >> 7, s = arow & 127;
    abase[j] = ((size_t)b*R_*S_ + s)*(size_t)F_ + (lane&7)*8;
    int orow = nt*256 + chunk*8 + (lane>>3);
    bbase[j] = (size_t)orow*F_ + (lane&7)*8;
  }
  f32x4 acc[8][4] = {};
  int wr = wid>>2, wc = wid&3;             // 2 (M) x 4 (N) waves, each 128x64 out
  int lr = lane&15, kk0 = (lane>>4)*8;
  int nsteps = nr*12;
  auto STAGE = [&](int bf, int step){
    int r = r0 + step/12, it = step%12;
    const f16* Ar = G  + (size_t)r*S_*F_;
    const f16* Br = WT + (size_t)r*F_*F_;
    #pragma unroll
    for (int j=0;j<4;j++){
      int chunk = wid*4 + j;
      GLD16(Ar + abase[j] + it*64, &ls[bf][0][chunk*512]);
      GLD16(Br + bbase[j] + it*64, &ls[bf][1][chunk*512]);
    }
  };
  STAGE(0, 0);
  __syncthreads();
  int cur = 0;
  for (int step=0; step<nsteps; ++step){
    if (step+1 < nsteps) STAGE(cur^1, step+1);   // prefetch next K-step
    __builtin_amdgcn_s_setprio(1);
    #pragma unroll
    for (int ks=0;ks<2;ks++){
      int kk = ks*32 + kk0;
      f16x8 av[8], bv[4];
      #pragma unroll
      for (int i=0;i<8;i++) av[i] = *(const f16x8*)&ls[cur][0][(wr*128+i*16+lr)*64 + kk];
      #pragma unroll
      for (int i=0;i<4;i++) bv[i] = *(const f16x8*)&ls[cur][1][(wc*64+i*16+lr)*64 + kk];
      #pragma unroll
      for (int mi=0;mi<8;mi++)
        #pragma unroll
        for (int ni=0;ni<4;ni++)
          acc[mi][ni] = __builtin_amdgcn_mfma_f32_16x16x32_f16(av[mi],bv[ni],acc[mi][ni],0,0,0);
    }
    __builtin_amdgcn_s_setprio(0);
    __syncthreads();                             // drains vmcnt+lgkmcnt: next buf ready
    cur ^= 1;
  }
  #pragma unroll
  for (int mi=0;mi<8;mi++)
    #pragma unroll
    for (int ni=0;ni<4;ni++){
      int row = mt*256 + wr*128 + mi*16 + (lane>>4)*4;
      int col = nt*256 + wc*64 + ni*16 + lr;
      #pragma unroll
      for (int i=0;i<4;i++)
        Cp[((size_t)g*BS_ + row + i)*F_ + col] = acc[mi][ni][i];
    }
}

// ---------------- reduce split-K partials, /SM, relu, write h32 + h16 ----------------
__global__ __launch_bounds__(256) void kReduce(const float* __restrict__ Cp, float* __restrict__ h32, f16* __restrict__ h16o) {
  int t = blockIdx.x*256 + threadIdx.x;
  size_t i4 = (size_t)t*4;
  f32x4 s = {};
  #pragma unroll
  for (int g=0; g<NG_; g++){
    f32x4 v4 = *(const f32x4*)(Cp + (size_t)g*BS_*F_ + i4);
    s.x += v4.x; s.y += v4.y; s.z += v4.z; s.w += v4.w;
  }
  const float inv = 1.0f/SM_SCALE;
  f32x4 rr;
  rr.x = fmaxf(s.x*inv, 0.f); rr.y = fmaxf(s.y*inv, 0.f);
  rr.z = fmaxf(s.z*inv, 0.f); rr.w = fmaxf(s.w*inv, 0.f);
  *(f32x4*)(h32 + i4) = rr;
  f16x4 o; o[0]=(f16)rr.x; o[1]=(f16)rr.y; o[2]=(f16)rr.z; o[3]=(f16)rr.w;
  *(f16x4*)(h16o + i4) = o;
}

// ---------------- kx = h2 @ wk + bk  (1024x768x768, MFMA, 2-phase prefetch) ----------------
__global__ __launch_bounds__(256) void kKx(const f16* __restrict__ A, const f16* __restrict__ BT,
                    const float* __restrict__ bias, float* __restrict__ C) {
  __shared__ f16 ls[2][2][128*64];   // 64 KB
  int bid = blockIdx.x;
  int nt = bid % 6, mt = bid / 6;
  int tid = threadIdx.x, wid = tid>>6, lane = tid&63;
  size_t abase[4], bbase[4];
  #pragma unroll
  for (int j=0;j<4;j++){
    int qd = wid*4 + j;
    int row = mt*128 + qd*8 + (lane>>3);
    abase[j] = (size_t)row*F_ + (lane&7)*8;
    int o = nt*128 + qd*8 + (lane>>3);
    bbase[j] = (size_t)o*F_ + (lane&7)*8;
  }
  f32x4 acc[4][4] = {};
  int wr = wid>>1, wc = wid&1;
  int lr = lane&15, kk0 = (lane>>4)*8;
  auto STAGE = [&](int bf, int it){
    #pragma unroll
    for (int j=0;j<4;j++){
      int qd = wid*4+j;
      GLD16(A + abase[j] + it*64, &ls[bf][0][qd*512]);
      GLD16(BT + bbase[j] + it*64, &ls[bf][1][qd*512]);
    }
  };
  STAGE(0, 0);
  __syncthreads();
  int cur = 0;
  for (int it=0; it<12; ++it){
    if (it+1 < 12) STAGE(cur^1, it+1);
    #pragma unroll
    for (int ks=0;ks<2;ks++){
      int kk = ks*32 + kk0;
      f16x8 av[4], bv[4];
      #pragma unroll
      for (int i=0;i<4;i++) av[i] = *(const f16x8*)&ls[cur][0][(wr*64+i*16+lr)*64 + kk];
      #pragma unroll
      for (int i=0;i<4;i++) bv[i] = *(const f16x8*)&ls[cur][1][(wc*64+i*16+lr)*64 + kk];
      #pragma unroll
      for (int mi=0;mi<4;mi++)
        #pragma unroll
        for (int ni=0;ni<4;ni++)
          acc[mi][ni] = __builtin_amdgcn_mfma_f32_16x16x32_f16(av[mi],bv[ni],acc[mi][ni],0,0,0);
    }
    __syncthreads();
    cur ^= 1;
  }
  #pragma unroll
  for (int mi=0;mi<4;mi++)
    #pragma unroll
    for (int ni=0;ni<4;ni++){
      int row = mt*128 + wr*64 + mi*16 + (lane>>4)*4;
      int col = nt*128 + wc*64 + ni*16 + lr;
      float bb = bias[col];
      #pragma unroll
      for (int i=0;i<4;i++)
        C[(size_t)(row+i)*F_ + col] = acc[mi][ni][i] + bb;
    }
}

// ---------------- attention core per (b,h): qx, qw, score, softmax, o ----------------
__global__ __launch_bounds__(256) void kAttn(const float* __restrict__ kx, const float* __restrict__ qin,
                      const float* __restrict__ wq, const float* __restrict__ bq,
                      const float* __restrict__ wbil, float* __restrict__ obuf) {
  int bid = blockIdx.x; int h = bid & 7; int b = bid >> 3;
  __shared__ float qx[HID_], qw[HID_], sc[S_];
  __shared__ float smax, ssum;
  int t = threadIdx.x;
  if (t < HID_) {
    float a0=0.f,a1=0.f,a2=0.f,a3=0.f;
    const float* qp = qin + (size_t)b*F_;
    const float* wp = wq + h*HID_ + t;
    for (int i=0;i<F_;i+=4){
      a0 += qp[i]*wp[(size_t)i*F_];
      a1 += qp[i+1]*wp[(size_t)(i+1)*F_];
      a2 += qp[i+2]*wp[(size_t)(i+2)*F_];
      a3 += qp[i+3]*wp[(size_t)(i+3)*F_];
    }
    qx[t] = a0+a1+a2+a3 + bq[h*HID_+t];
  }
  __syncthreads();
  if (t < HID_) {
    float a0=0.f,a1=0.f;
    for (int e=0;e<HID_;e+=2){ a0 += qx[e]*wbil[e*HID_+t]; a1 += qx[e+1]*wbil[(e+1)*HID_+t]; }
    qw[t] = a0+a1;
  }
  __syncthreads();
  if (t < S_) {
    float a0=0.f,a1=0.f;
    const float* kp = kx + ((size_t)b*S_ + t)*F_ + h*HID_;
    for (int e=0;e<HID_;e+=2){ a0 += qw[e]*kp[e]; a1 += qw[e+1]*kp[e+1]; }
    sc[t] = a0+a1;
  }
  __syncthreads();
  if (t < 64) {
    float m = fmaxf(sc[t], sc[t+64]);
    #pragma unroll
    for (int o=32;o;o>>=1) m = fmaxf(m, __shfl_down(m,o,64));
    if (t==0) smax = m;
  }
  __syncthreads();
  if (t < S_) sc[t] = expf(sc[t]-smax);
  __syncthreads();
  if (t < 64) {
    float s = sc[t] + sc[t+64];
    s = wredsum(s);
    if (t==0) ssum = s;
  }
  __syncthreads();
  if (t < HID_) {
    float a0=0.f,a1=0.f;
    const float* kp = kx + ((size_t)b*S_)*F_ + h*HID_ + t;
    for (int k=0;k<S_;k+=2){ a0 += sc[k]*kp[(size_t)k*F_]; a1 += sc[k+1]*kp[(size_t)(k+1)*F_]; }
    obuf[(size_t)b*F_ + h*HID_ + t] = (a0+a1)/ssum;
  }
}

// ---------------- final projection out = o @ wproj + bproj ----------------
__global__ __launch_bounds__(256) void kProj(const float* __restrict__ obuf, const float* __restrict__ wproj,
                      const float* __restrict__ bproj, float* __restrict__ outp) {
  int bid = blockIdx.x; int b = bid/3, seg = bid%3;
  int t = threadIdx.x;
  __shared__ float ov[F_];
  for (int j=t;j<F_;j+=256) ov[j] = obuf[(size_t)b*F_ + j];
  __syncthreads();
  int col = seg*256 + t;
  float a0=0.f,a1=0.f,a2=0.f,a3=0.f;
  for (int j=0;j<F_;j+=4){
    a0 += ov[j]*wproj[(size_t)j*F_+col];
    a1 += ov[j+1]*wproj[(size_t)(j+1)*F_+col];
    a2 += ov[j+2]*wproj[(size_t)(j+2)*F_+col];
    a3 += ov[j+3]*wproj[(size_t)(j+3)*F_+col];
  }
  outp[(size_t)b*F_ + col] = bproj[col] + a0+a1+a2+a3;
}

extern "C" void kernel_launch(void* const* d_in, const int* in_sizes, int n_in,
                              void* d_out, int out_size, void* d_ws, size_t ws_size,
                              hipStream_t stream) {
  (void)in_sizes; (void)n_in; (void)out_size;
  const float* x      = (const float*)d_in[0];
  const float* adj    = (const float*)d_in[1];
  const float* qin    = (const float*)d_in[2];
  const float* w_rgcn = (const float*)d_in[3];
  const float* score_w= (const float*)d_in[4];
  const float* score_b= (const float*)d_in[5];
  const float* wk     = (const float*)d_in[6];
  const float* bk     = (const float*)d_in[7];
  const float* wq     = (const float*)d_in[8];
  const float* bq     = (const float*)d_in[9];
  const float* wbil   = (const float*)d_in[10];
  const float* wproj  = (const float*)d_in[11];
  const float* bproj  = (const float*)d_in[12];
  float* outp = (float*)d_out;

  char* p = (char*)d_ws;
  auto alloc = [&](size_t bytes)->char* {
    char* r = p; p += (bytes + 255) & ~(size_t)255; return r;
  };
  f16*   w16T  = (f16*)  alloc((size_t)R_*F_*F_*2);
  f16*   G16   = (f16*)  alloc((size_t)B_*R_*S_*F_*2);
  f16*   M16   = (f16*)  alloc((size_t)B_*R_*S_*S_*2);
  float* Cpart = (float*)alloc((size_t)NG_*BS_*F_*4);
  float* h32a  = (float*)alloc((size_t)BS_*F_*4);
  float* h32b  = (float*)alloc((size_t)BS_*F_*4);
  f16*   h16row= (f16*)  alloc((size_t)BS_*F_*2);
  f16*   h16T  = (f16*)  alloc((size_t)BS_*F_*2);
  float* kx    = (float*)alloc((size_t)BS_*F_*4);
  f16*   wkT   = (f16*)  alloc((size_t)F_*F_*2);
  float* vbuf  = (float*)alloc((size_t)R_*F_*4);
  float* dinv  = (float*)alloc((size_t)B_*R_*S_*4);
  float* lgb   = (float*)alloc((size_t)B_*R_*S_*4);
  float* obuf  = (float*)alloc((size_t)B_*F_*4);
  if ((size_t)(p - (char*)d_ws) > ws_size) return;  // workspace insufficient -> fail loudly

  const size_t WL = (size_t)R_*F_*F_;   // w_rgcn layer stride

  // ---- layer 0 (h = x) ----
  kConvWV<<<R_*12, 256, 0, stream>>>(w_rgcn, score_w, w16T, vbuf);
  kTransTo16T<float><<<192, 256, 0, stream>>>(x, h16T);
  kUL<<<B_*R_, 256, 0, stream>>>(x, vbuf, adj, score_b, 0, dinv, lgb);
  kSM16<<<B_*S_, 64, 0, stream>>>(lgb, dinv, adj, M16);
  kGgemm<<<B_*R_*6, 256, 0, stream>>>(M16, h16T, G16);
  kOutGemm<<<12*NG_, 512, 0, stream>>>(G16, w16T, Cpart);
  kReduce<<<768, 256, 0, stream>>>(Cpart, h32a, h16row);
  kTransTo16T<f16><<<192, 256, 0, stream>>>(h16row, h16T);

  // ---- layer 1 (h = h32a) ----
  kConvWV<<<R_*12, 256, 0, stream>>>(w_rgcn + WL, score_w + F_, w16T, vbuf);
  kUL<<<B_*R_, 256, 0, stream>>>(h32a, vbuf, adj, score_b, 1, dinv, lgb);
  kSM16<<<B_*S_, 64, 0, stream>>>(lgb, dinv, adj, M16);
  kGgemm<<<B_*R_*6, 256, 0, stream>>>(M16, h16T, G16);
  kOutGemm<<<12*NG_, 512, 0, stream>>>(G16, w16T, Cpart);
  kReduce<<<768, 256, 0, stream>>>(Cpart, h32b, h16row);

  // ---- attention ----
  kConvW<<<144, 256, 0, stream>>>(wk, wkT);
  kKx<<<48, 256, 0, stream>>>(h16row, wkT, bk, kx);
  kAttn<<<64, 256, 0, stream>>>(kx, qin, wq, bq, wbil, obuf);
  kProj<<<24, 256, 0, stream>>>(obuf, wproj, bproj, outp);
}